// Round 7
// baseline (2690.994 us; speedup 1.0000x reference)
//
#include <hip/hip_runtime.h>
#include <math.h>

#define N_NODES 100000
#define NREL 3
#define E_PER 1600000
#define EP 500000
#define F_IN 128
#define F_HID 64
#define F_OUT 16

// ws layout (float offsets)
#define DINV_OUT_OFF 0          // 3*100000
#define DINV_IN_OFF  300000     // 3*100000
#define H1ACC_OFF    600000     // 100000*64
#define HPROJ_OFF    7000000    // 100000*64 (reused as 100000*32 for layer2)
#define L2ACC_OFF    13400000   // 100000*32

__device__ __forceinline__ float atomAddF(float* p, float v) {
    return unsafeAtomicAdd(p, v);  // R3(CAS) vs R4(unsafe) bit-identical => safe here
}

__device__ __forceinline__ unsigned rotl32(unsigned x, unsigned d) {
    return (x << d) | (x >> (32u - d));
}

// jax.random.normal(key(42), (100000,16), f32), element i, partitionable mode:
// counter = u64 flat index -> threefry2x32 (x0 = hi = 0, x1 = lo = i), key (0,42).
// bit_width==32 partitionable path XOR-FOLDS the two output words: bits = o0 ^ o1.
// [tested wrong: legacy-split 44.4, o0-only 42.1, o1-only 46.2]
__device__ float jax_noise(unsigned i) {
    const unsigned ks0 = 0u, ks1 = 42u;
    const unsigned ks2 = ks0 ^ ks1 ^ 0x1BD11BDAu;
    unsigned x0 = 0u + ks0;
    unsigned x1 = i + ks1;
#define TFR(r) { x0 += x1; x1 = rotl32(x1, r); x1 ^= x0; }
    TFR(13) TFR(15) TFR(26) TFR(6)
    x0 += ks1; x1 += ks2 + 1u;
    TFR(17) TFR(29) TFR(16) TFR(24)
    x0 += ks2; x1 += ks0 + 2u;
    TFR(13) TFR(15) TFR(26) TFR(6)
    x0 += ks0; x1 += ks1 + 3u;
    TFR(17) TFR(29) TFR(16) TFR(24)
    x0 += ks1; x1 += ks2 + 4u;
    TFR(13) TFR(15) TFR(26) TFR(6)
    x0 += ks2; x1 += ks0 + 5u;
#undef TFR
    const unsigned bits = x0 ^ x1;   // XOR fold  <-- changed this round
    float f = __uint_as_float((bits >> 9) | 0x3f800000u) - 1.0f;  // [0,1)
    const float lo = -0.99999994f;
    float u = fmaxf(lo, f * 2.0f + lo);
    float w = -log1pf(-u * u);
    float p;
    if (w < 5.0f) {
        w -= 2.5f;
        p = 2.81022636e-08f;
        p = fmaf(p, w, 3.43273939e-07f);
        p = fmaf(p, w, -3.5233877e-06f);
        p = fmaf(p, w, -4.39150654e-06f);
        p = fmaf(p, w, 0.00021858087f);
        p = fmaf(p, w, -0.00125372503f);
        p = fmaf(p, w, -0.00417768164f);
        p = fmaf(p, w, 0.246640727f);
        p = fmaf(p, w, 1.50140941f);
    } else {
        w = sqrtf(w) - 3.0f;
        p = -0.000200214257f;
        p = fmaf(p, w, 0.000100950558f);
        p = fmaf(p, w, 0.00134934322f);
        p = fmaf(p, w, -0.00367342844f);
        p = fmaf(p, w, 0.00573950773f);
        p = fmaf(p, w, -0.0076224613f);
        p = fmaf(p, w, 0.00943887047f);
        p = fmaf(p, w, 1.00167406f);
        p = fmaf(p, w, 2.83297682f);
    }
    return 1.41421356237f * (p * u);
}

__global__ __launch_bounds__(256) void k_degrees(const int* __restrict__ es,
                                                 const int* __restrict__ ed,
                                                 float* __restrict__ dout,
                                                 float* __restrict__ din) {
    const int r = blockIdx.y;
    const int e = blockIdx.x * 256 + threadIdx.x;
    const int s = es[r * E_PER + e];
    const int d = ed[r * E_PER + e];
    atomAddF(&dout[r * N_NODES + s], 1.0f);
    atomAddF(&din[r * N_NODES + d], 1.0f);
}

__global__ __launch_bounds__(256) void k_finalize_deg(float* __restrict__ d) {
    const int i = blockIdx.x * 256 + threadIdx.x;
    if (i < 2 * NREL * N_NODES) d[i] = 1.0f / sqrtf(fmaxf(d[i], 1.0f));
}

__global__ __launch_bounds__(256) void k_project1(const float* __restrict__ x,
                                                  const float* __restrict__ W,
                                                  const float* __restrict__ dinv,
                                                  float* __restrict__ out) {
    __shared__ float ws[F_IN * F_HID];
    for (int i = threadIdx.x; i < F_IN * F_HID; i += 256) ws[i] = W[i];
    __syncthreads();
    const int t = blockIdx.x * 256 + threadIdx.x;
    const int n = t >> 6;
    const int c = t & 63;
    const float* xr = x + (size_t)n * F_IN;
    float acc = 0.f;
#pragma unroll 16
    for (int k = 0; k < F_IN; ++k) acc = fmaf(xr[k], ws[k * F_HID + c], acc);
    out[t] = acc * dinv[n];
}

__global__ __launch_bounds__(256) void k_scatter1(const float* __restrict__ hp,
                                                  const int* __restrict__ es,
                                                  const int* __restrict__ ed,
                                                  const float* __restrict__ din,
                                                  float* __restrict__ acc) {
    const int t = blockIdx.x * 256 + threadIdx.x;
    const int e = t >> 6;
    const int lane = t & 63;
    const int s = es[e];
    const int d = ed[e];
    const float v = hp[s * F_HID + lane] * din[d];
    atomAddF(&acc[d * F_HID + lane], v);
}

__global__ __launch_bounds__(256) void k_project2(const float* __restrict__ h1,
                                                  const float* __restrict__ b0,
                                                  const float* __restrict__ Wmu,
                                                  const float* __restrict__ Wls,
                                                  const float* __restrict__ dinv,
                                                  float* __restrict__ out) {
    __shared__ float ws[F_HID * 32];
    __shared__ float bs[F_HID];
    for (int i = threadIdx.x; i < F_HID * 32; i += 256) {
        const int k = i >> 5, c = i & 31;
        ws[i] = (c < 16) ? Wmu[k * 16 + c] : Wls[k * 16 + (c - 16)];
    }
    if (threadIdx.x < F_HID)
        bs[threadIdx.x] = b0[threadIdx.x] + b0[64 + threadIdx.x] + b0[128 + threadIdx.x];
    __syncthreads();
    const int t = blockIdx.x * 256 + threadIdx.x;
    const int n = t >> 5;
    const int c = t & 31;
    const float* hr = h1 + (size_t)n * F_HID;
    float acc = 0.f;
#pragma unroll 8
    for (int k = 0; k < F_HID; ++k) {
        const float v = fmaxf(hr[k] + bs[k], 0.f);
        acc = fmaf(v, ws[k * 32 + c], acc);
    }
    out[t] = acc * dinv[n];
}

__global__ __launch_bounds__(256) void k_scatter2(const float* __restrict__ hp,
                                                  const int* __restrict__ es,
                                                  const int* __restrict__ ed,
                                                  const float* __restrict__ din,
                                                  float* __restrict__ acc) {
    const int t = blockIdx.x * 256 + threadIdx.x;
    const int e = t >> 5;
    const int c = t & 31;
    const int s = es[e];
    const int d = ed[e];
    const float v = hp[s * 32 + c] * din[d];
    atomAddF(&acc[d * 32 + c], v);
}

__global__ __launch_bounds__(256) void k_finalize(const float* __restrict__ l2,
                                                  const float* __restrict__ bmu,
                                                  const float* __restrict__ bls,
                                                  float* __restrict__ outh) {
    const int i = blockIdx.x * 256 + threadIdx.x;
    const int n = i >> 4, c = i & 15;
    const float mean = l2[n * 32 + c] + bmu[c] + bmu[16 + c] + bmu[32 + c];
    const float lstd = l2[n * 32 + 16 + c] + bls[c] + bls[16 + c] + bls[32 + c];
    const float z = jax_noise((unsigned)i);
    outh[i] = mean + z * expf(lstd);
}

__global__ __launch_bounds__(256) void k_scores(const int* __restrict__ ps,
                                                const int* __restrict__ pd,
                                                const int* __restrict__ ns,
                                                const int* __restrict__ nd,
                                                const float* __restrict__ h,
                                                float* __restrict__ out) {
    const int i = blockIdx.x * 256 + threadIdx.x;
    if (i >= 2 * EP) return;
    const int j = (i < EP) ? i : i - EP;
    const int a = (i < EP) ? ps[j] : ns[j];
    const int b = (i < EP) ? pd[j] : nd[j];
    const float4* ha = (const float4*)(h + (size_t)a * 16);
    const float4* hb = (const float4*)(h + (size_t)b * 16);
    float s = 0.f;
#pragma unroll
    for (int q = 0; q < 4; ++q) {
        const float4 u = ha[q];
        const float4 v = hb[q];
        s += u.x * v.x + u.y * v.y + u.z * v.z + u.w * v.w;
    }
    out[i] = s;
}

extern "C" void kernel_launch(void* const* d_in, const int* in_sizes, int n_in,
                              void* d_out, int out_size, void* d_ws, size_t ws_size,
                              hipStream_t stream) {
    const float* x   = (const float*)d_in[0];
    const float* W0  = (const float*)d_in[1];
    const float* b0  = (const float*)d_in[2];
    const float* Wmu = (const float*)d_in[3];
    const float* bmu = (const float*)d_in[4];
    const float* Wls = (const float*)d_in[5];
    const float* bls = (const float*)d_in[6];
    const int* es = (const int*)d_in[7];
    const int* ed = (const int*)d_in[8];
    const int* ps = (const int*)d_in[9];
    const int* pd = (const int*)d_in[10];
    const int* ns = (const int*)d_in[11];
    const int* nd = (const int*)d_in[12];
    float* out = (float*)d_out;
    float* wsf = (float*)d_ws;

    float* dinv_out = wsf + DINV_OUT_OFF;
    float* dinv_in  = wsf + DINV_IN_OFF;
    float* h1acc    = wsf + H1ACC_OFF;
    float* hproj    = wsf + HPROJ_OFF;
    float* l2acc    = wsf + L2ACC_OFF;

    hipMemsetAsync(dinv_out, 0, (size_t)2 * NREL * N_NODES * sizeof(float), stream);
    hipMemsetAsync(h1acc, 0, (size_t)N_NODES * F_HID * sizeof(float), stream);
    hipMemsetAsync(l2acc, 0, (size_t)N_NODES * 32 * sizeof(float), stream);

    k_degrees<<<dim3(E_PER / 256, NREL), 256, 0, stream>>>(es, ed, dinv_out, dinv_in);
    k_finalize_deg<<<(2 * NREL * N_NODES + 255) / 256, 256, 0, stream>>>(wsf);

    for (int r = 0; r < NREL; ++r) {
        k_project1<<<N_NODES * F_HID / 256, 256, 0, stream>>>(
            x, W0 + (size_t)r * F_IN * F_HID, dinv_out + (size_t)r * N_NODES, hproj);
        k_scatter1<<<E_PER / 4, 256, 0, stream>>>(
            hproj, es + (size_t)r * E_PER, ed + (size_t)r * E_PER,
            dinv_in + (size_t)r * N_NODES, h1acc);
    }
    for (int r = 0; r < NREL; ++r) {
        k_project2<<<N_NODES * 32 / 256, 256, 0, stream>>>(
            h1acc, b0, Wmu + (size_t)r * F_HID * F_OUT, Wls + (size_t)r * F_HID * F_OUT,
            dinv_out + (size_t)r * N_NODES, hproj);
        k_scatter2<<<E_PER / 8, 256, 0, stream>>>(
            hproj, es + (size_t)r * E_PER, ed + (size_t)r * E_PER,
            dinv_in + (size_t)r * N_NODES, l2acc);
    }
    k_finalize<<<N_NODES * F_OUT / 256, 256, 0, stream>>>(
        l2acc, bmu, bls, out + 2 * EP);
    k_scores<<<(2 * EP + 255) / 256, 256, 0, stream>>>(
        ps, pd, ns, nd, out + 2 * EP, out);
}

// Round 8
// 1887.958 us; speedup vs baseline: 1.4253x; 1.4253x over previous
//
#include <hip/hip_runtime.h>
#include <math.h>

#define N_NODES 100000
#define NREL 3
#define E_PER 1600000
#define E_TOT 4800000
#define EP 500000
#define F_IN 128
#define F_HID 64
#define F_OUT 16
#define NRN 300000   // NREL*N_NODES

// ---------------- CSR-path ws layout (element offsets) ----------------
#define OFF_DOUT    0           // 300000 f: out-deg hist -> rsqrt in place (dinv_out)
#define OFF_DINVIN  300000      // 300000 f
#define OFF_CNT     600000      // 300000 i: in-deg counts -> reused as fill cursor
#define OFF_G       900000      // 300000 i: global exclusive prefix (CSR offsets)
#define OFF_BSUM    1200000     // 1024 i
#define OFF_CSR     1201024     // 4800000 i: dst-sorted src indices
#define OFF_HPROJ   6001024     // 6400000 f
#define OFF_H1      12401024    // 6400000 f
#define OFF_L2      18801024    // 3200000 f
#define WS_NEED_CSR 22001024
// ---------------- fallback (R7 atomic-scatter) layout ----------------
#define ODINV_OUT 0
#define ODINV_IN  300000
#define OH1ACC    600000
#define OHPROJ    7000000
#define OL2ACC    13400000

__device__ __forceinline__ float atomAddF(float* p, float v) {
    return unsafeAtomicAdd(p, v);  // proven identical to CAS path (R3 vs R4)
}

__device__ __forceinline__ unsigned rotl32(unsigned x, unsigned d) {
    return (x << d) | (x >> (32u - d));
}

// jax.random.normal(key(42), (100000,16)) — partitionable threefry2x32,
// counter (0,i), key (0,42), XOR-folded output words. Verified PASS in R7.
__device__ float jax_noise(unsigned i) {
    const unsigned ks0 = 0u, ks1 = 42u;
    const unsigned ks2 = ks0 ^ ks1 ^ 0x1BD11BDAu;
    unsigned x0 = 0u + ks0;
    unsigned x1 = i + ks1;
#define TFR(r) { x0 += x1; x1 = rotl32(x1, r); x1 ^= x0; }
    TFR(13) TFR(15) TFR(26) TFR(6)
    x0 += ks1; x1 += ks2 + 1u;
    TFR(17) TFR(29) TFR(16) TFR(24)
    x0 += ks2; x1 += ks0 + 2u;
    TFR(13) TFR(15) TFR(26) TFR(6)
    x0 += ks0; x1 += ks1 + 3u;
    TFR(17) TFR(29) TFR(16) TFR(24)
    x0 += ks1; x1 += ks2 + 4u;
    TFR(13) TFR(15) TFR(26) TFR(6)
    x0 += ks2; x1 += ks0 + 5u;
#undef TFR
    const unsigned bits = x0 ^ x1;
    float f = __uint_as_float((bits >> 9) | 0x3f800000u) - 1.0f;
    const float lo = -0.99999994f;
    float u = fmaxf(lo, f * 2.0f + lo);
    float w = -log1pf(-u * u);
    float p;
    if (w < 5.0f) {
        w -= 2.5f;
        p = 2.81022636e-08f;
        p = fmaf(p, w, 3.43273939e-07f);
        p = fmaf(p, w, -3.5233877e-06f);
        p = fmaf(p, w, -4.39150654e-06f);
        p = fmaf(p, w, 0.00021858087f);
        p = fmaf(p, w, -0.00125372503f);
        p = fmaf(p, w, -0.00417768164f);
        p = fmaf(p, w, 0.246640727f);
        p = fmaf(p, w, 1.50140941f);
    } else {
        w = sqrtf(w) - 3.0f;
        p = -0.000200214257f;
        p = fmaf(p, w, 0.000100950558f);
        p = fmaf(p, w, 0.00134934322f);
        p = fmaf(p, w, -0.00367342844f);
        p = fmaf(p, w, 0.00573950773f);
        p = fmaf(p, w, -0.0076224613f);
        p = fmaf(p, w, 0.00943887047f);
        p = fmaf(p, w, 1.00167406f);
        p = fmaf(p, w, 2.83297682f);
    }
    return 1.41421356237f * (p * u);
}

// ---------------------------------------------------------------- CSR path
// int in-degree counts + float out-degree histogram. grid (6250,3) x 256.
__global__ __launch_bounds__(256) void k_hist(const int* __restrict__ es,
                                              const int* __restrict__ ed,
                                              int* __restrict__ cnt,
                                              float* __restrict__ dout) {
    const int r = blockIdx.y;
    const int e = blockIdx.x * 256 + threadIdx.x;
    const int s = es[r * E_PER + e];
    const int d = ed[r * E_PER + e];
    atomicAdd(&cnt[r * N_NODES + d], 1);
    atomAddF(&dout[r * N_NODES + s], 1.0f);
}

// block sums over 1024-element spans of cnt. grid 294 x 256.
__global__ __launch_bounds__(256) void k_scanA(const int* __restrict__ cnt,
                                               int* __restrict__ bsum) {
    __shared__ int red[256];
    const int base = blockIdx.x * 1024 + threadIdx.x * 4;
    int s = 0;
#pragma unroll
    for (int q = 0; q < 4; ++q) {
        const int i = base + q;
        s += (i < NRN) ? cnt[i] : 0;
    }
    red[threadIdx.x] = s;
    __syncthreads();
    for (int w = 128; w > 0; w >>= 1) {
        if (threadIdx.x < w) red[threadIdx.x] += red[threadIdx.x + w];
        __syncthreads();
    }
    if (threadIdx.x == 0) bsum[blockIdx.x] = red[0];
}

// exclusive scan of 294 block sums (in place). 1 block x 512.
__global__ __launch_bounds__(512) void k_scanB(int* __restrict__ bsum) {
    __shared__ int sc[512];
    const int t = threadIdx.x;
    sc[t] = (t < 294) ? bsum[t] : 0;
    __syncthreads();
    for (int o = 1; o < 512; o <<= 1) {
        const int v = (t >= o) ? sc[t - o] : 0;
        __syncthreads();
        sc[t] += v;
        __syncthreads();
    }
    bsum[t] = (t > 0) ? sc[t - 1] : 0;
}

// add-back: G = global exclusive prefix; dinv_in = rsqrt(max(cnt,1));
// cnt := 0 (becomes fill cursor); dout := rsqrt(max(dout,1)) in place.
__global__ __launch_bounds__(256) void k_scanC(int* __restrict__ cnt,
                                               const int* __restrict__ bsum,
                                               int* __restrict__ G,
                                               float* __restrict__ dinv_in,
                                               float* __restrict__ dout) {
    __shared__ int sc[256];
    const int t = threadIdx.x;
    const int base = blockIdx.x * 1024 + t * 4;
    int v[4];
    int ts = 0;
#pragma unroll
    for (int q = 0; q < 4; ++q) {
        const int i = base + q;
        v[q] = (i < NRN) ? cnt[i] : 0;
        ts += v[q];
    }
    sc[t] = ts;
    __syncthreads();
    for (int o = 1; o < 256; o <<= 1) {
        const int x = (t >= o) ? sc[t - o] : 0;
        __syncthreads();
        sc[t] += x;
        __syncthreads();
    }
    int run = bsum[blockIdx.x] + ((t > 0) ? sc[t - 1] : 0);
#pragma unroll
    for (int q = 0; q < 4; ++q) {
        const int i = base + q;
        if (i < NRN) {
            G[i] = run;
            dinv_in[i] = rsqrtf((float)max(v[q], 1));
            cnt[i] = 0;
            dout[i] = rsqrtf(fmaxf(dout[i], 1.0f));
        }
        run += v[q];
    }
}

// dst-sorted CSR fill. grid (6250,3) x 256.
__global__ __launch_bounds__(256) void k_fill(const int* __restrict__ es,
                                              const int* __restrict__ ed,
                                              int* __restrict__ cursor,
                                              const int* __restrict__ G,
                                              int* __restrict__ csr) {
    const int r = blockIdx.y;
    const int e = blockIdx.x * 256 + threadIdx.x;
    const int s = es[r * E_PER + e];
    const int d = ed[r * E_PER + e];
    const int idx = r * N_NODES + d;
    const int slot = atomicAdd(&cursor[idx], 1);
    csr[G[idx] + slot] = s;
}

// atomic-free aggregation, 64 feats: one wave per dst node. grid 25000 x 256.
__global__ __launch_bounds__(256) void k_gather1(const float* __restrict__ hp,
                                                 const int* __restrict__ csr,
                                                 const int* __restrict__ G,
                                                 const float* __restrict__ dinv,
                                                 float* __restrict__ h1,
                                                 int rbase, int first) {
    const int t = blockIdx.x * 256 + threadIdx.x;
    const int n = t >> 6;
    const int lane = t & 63;
    const int idx = rbase + n;
    const int off0 = G[idx];
    const int off1 = (idx == NRN - 1) ? E_TOT : G[idx + 1];
    float sum = 0.f;
    for (int base = off0; base < off1; base += 64) {
        int m = off1 - base;
        if (m > 64) m = 64;
        const int sv = (lane < m) ? csr[base + lane] : 0;
        for (int j = 0; j < m; ++j) {
            const int s = __shfl(sv, j);
            sum += hp[s * F_HID + lane];
        }
    }
    const float v = dinv[idx] * sum;
    if (first) h1[n * F_HID + lane] = v;
    else       h1[n * F_HID + lane] += v;
}

// atomic-free aggregation, 32 feats (mu||ls): 32 lanes per node. grid 12500 x 256.
__global__ __launch_bounds__(256) void k_gather2(const float* __restrict__ hp,
                                                 const int* __restrict__ csr,
                                                 const int* __restrict__ G,
                                                 const float* __restrict__ dinv,
                                                 float* __restrict__ l2,
                                                 int rbase, int first) {
    const int t = blockIdx.x * 256 + threadIdx.x;
    const int n = t >> 5;
    const int c = t & 31;
    const int idx = rbase + n;
    const int off0 = G[idx];
    const int off1 = (idx == NRN - 1) ? E_TOT : G[idx + 1];
    float sum = 0.f;
    for (int base = off0; base < off1; base += 32) {
        int m = off1 - base;
        if (m > 32) m = 32;
        const int sv = (c < m) ? csr[base + c] : 0;
        for (int j = 0; j < m; ++j) {
            const int s = __shfl(sv, j, 32);
            sum += hp[s * 32 + c];
        }
    }
    const float v = dinv[idx] * sum;
    if (first) l2[n * 32 + c] = v;
    else       l2[n * 32 + c] += v;
}

// ------------------------------------------------------ shared projections
__global__ __launch_bounds__(256) void k_project1(const float* __restrict__ x,
                                                  const float* __restrict__ W,
                                                  const float* __restrict__ dinv,
                                                  float* __restrict__ out) {
    __shared__ float ws[F_IN * F_HID];
    for (int i = threadIdx.x; i < F_IN * F_HID; i += 256) ws[i] = W[i];
    __syncthreads();
    const int t = blockIdx.x * 256 + threadIdx.x;
    const int n = t >> 6;
    const int c = t & 63;
    const float* xr = x + (size_t)n * F_IN;
    float acc = 0.f;
#pragma unroll 16
    for (int k = 0; k < F_IN; ++k) acc = fmaf(xr[k], ws[k * F_HID + c], acc);
    out[t] = acc * dinv[n];
}

__global__ __launch_bounds__(256) void k_project2(const float* __restrict__ h1,
                                                  const float* __restrict__ b0,
                                                  const float* __restrict__ Wmu,
                                                  const float* __restrict__ Wls,
                                                  const float* __restrict__ dinv,
                                                  float* __restrict__ out) {
    __shared__ float ws[F_HID * 32];
    __shared__ float bs[F_HID];
    for (int i = threadIdx.x; i < F_HID * 32; i += 256) {
        const int k = i >> 5, c = i & 31;
        ws[i] = (c < 16) ? Wmu[k * 16 + c] : Wls[k * 16 + (c - 16)];
    }
    if (threadIdx.x < F_HID)
        bs[threadIdx.x] = b0[threadIdx.x] + b0[64 + threadIdx.x] + b0[128 + threadIdx.x];
    __syncthreads();
    const int t = blockIdx.x * 256 + threadIdx.x;
    const int n = t >> 5;
    const int c = t & 31;
    const float* hr = h1 + (size_t)n * F_HID;
    float acc = 0.f;
#pragma unroll 8
    for (int k = 0; k < F_HID; ++k) {
        const float v = fmaxf(hr[k] + bs[k], 0.f);
        acc = fmaf(v, ws[k * 32 + c], acc);
    }
    out[t] = acc * dinv[n];
}

__global__ __launch_bounds__(256) void k_finalize(const float* __restrict__ l2,
                                                  const float* __restrict__ bmu,
                                                  const float* __restrict__ bls,
                                                  float* __restrict__ outh) {
    const int i = blockIdx.x * 256 + threadIdx.x;
    const int n = i >> 4, c = i & 15;
    const float mean = l2[n * 32 + c] + bmu[c] + bmu[16 + c] + bmu[32 + c];
    const float lstd = l2[n * 32 + 16 + c] + bls[c] + bls[16 + c] + bls[32 + c];
    const float z = jax_noise((unsigned)i);
    outh[i] = mean + z * expf(lstd);
}

__global__ __launch_bounds__(256) void k_scores(const int* __restrict__ ps,
                                                const int* __restrict__ pd,
                                                const int* __restrict__ ns,
                                                const int* __restrict__ nd,
                                                const float* __restrict__ h,
                                                float* __restrict__ out) {
    const int i = blockIdx.x * 256 + threadIdx.x;
    if (i >= 2 * EP) return;
    const int j = (i < EP) ? i : i - EP;
    const int a = (i < EP) ? ps[j] : ns[j];
    const int b = (i < EP) ? pd[j] : nd[j];
    const float4* ha = (const float4*)(h + (size_t)a * 16);
    const float4* hb = (const float4*)(h + (size_t)b * 16);
    float s = 0.f;
#pragma unroll
    for (int q = 0; q < 4; ++q) {
        const float4 u = ha[q];
        const float4 v = hb[q];
        s += u.x * v.x + u.y * v.y + u.z * v.z + u.w * v.w;
    }
    out[i] = s;
}

// --------------------------------------------- fallback (R7 atomic-scatter)
__global__ __launch_bounds__(256) void k_degrees(const int* __restrict__ es,
                                                 const int* __restrict__ ed,
                                                 float* __restrict__ dout,
                                                 float* __restrict__ din) {
    const int r = blockIdx.y;
    const int e = blockIdx.x * 256 + threadIdx.x;
    const int s = es[r * E_PER + e];
    const int d = ed[r * E_PER + e];
    atomAddF(&dout[r * N_NODES + s], 1.0f);
    atomAddF(&din[r * N_NODES + d], 1.0f);
}

__global__ __launch_bounds__(256) void k_finalize_deg(float* __restrict__ d) {
    const int i = blockIdx.x * 256 + threadIdx.x;
    if (i < 2 * NRN) d[i] = 1.0f / sqrtf(fmaxf(d[i], 1.0f));
}

__global__ __launch_bounds__(256) void k_scatter1(const float* __restrict__ hp,
                                                  const int* __restrict__ es,
                                                  const int* __restrict__ ed,
                                                  const float* __restrict__ din,
                                                  float* __restrict__ acc) {
    const int t = blockIdx.x * 256 + threadIdx.x;
    const int e = t >> 6;
    const int lane = t & 63;
    const int s = es[e];
    const int d = ed[e];
    const float v = hp[s * F_HID + lane] * din[d];
    atomAddF(&acc[d * F_HID + lane], v);
}

__global__ __launch_bounds__(256) void k_scatter2(const float* __restrict__ hp,
                                                  const int* __restrict__ es,
                                                  const int* __restrict__ ed,
                                                  const float* __restrict__ din,
                                                  float* __restrict__ acc) {
    const int t = blockIdx.x * 256 + threadIdx.x;
    const int e = t >> 5;
    const int c = t & 31;
    const int s = es[e];
    const int d = ed[e];
    const float v = hp[s * 32 + c] * din[d];
    atomAddF(&acc[d * 32 + c], v);
}

extern "C" void kernel_launch(void* const* d_in, const int* in_sizes, int n_in,
                              void* d_out, int out_size, void* d_ws, size_t ws_size,
                              hipStream_t stream) {
    const float* x   = (const float*)d_in[0];
    const float* W0  = (const float*)d_in[1];
    const float* b0  = (const float*)d_in[2];
    const float* Wmu = (const float*)d_in[3];
    const float* bmu = (const float*)d_in[4];
    const float* Wls = (const float*)d_in[5];
    const float* bls = (const float*)d_in[6];
    const int* es = (const int*)d_in[7];
    const int* ed = (const int*)d_in[8];
    const int* ps = (const int*)d_in[9];
    const int* pd = (const int*)d_in[10];
    const int* ns = (const int*)d_in[11];
    const int* nd = (const int*)d_in[12];
    float* out = (float*)d_out;
    float* wsf = (float*)d_ws;

    if (ws_size >= (size_t)WS_NEED_CSR * sizeof(float)) {
        // ---------------- CSR path ----------------
        float* dout    = wsf + OFF_DOUT;     // -> dinv_out after scanC
        float* dinv_in = wsf + OFF_DINVIN;
        int*   cnt     = (int*)(wsf + OFF_CNT);
        int*   G       = (int*)(wsf + OFF_G);
        int*   bsum    = (int*)(wsf + OFF_BSUM);
        int*   csr     = (int*)(wsf + OFF_CSR);
        float* hproj   = wsf + OFF_HPROJ;
        float* h1acc   = wsf + OFF_H1;
        float* l2acc   = wsf + OFF_L2;

        hipMemsetAsync(dout, 0, (size_t)NRN * sizeof(float), stream);
        hipMemsetAsync(cnt, 0, (size_t)NRN * sizeof(int), stream);

        k_hist<<<dim3(E_PER / 256, NREL), 256, 0, stream>>>(es, ed, cnt, dout);
        k_scanA<<<294, 256, 0, stream>>>(cnt, bsum);
        k_scanB<<<1, 512, 0, stream>>>(bsum);
        k_scanC<<<294, 256, 0, stream>>>(cnt, bsum, G, dinv_in, dout);
        k_fill<<<dim3(E_PER / 256, NREL), 256, 0, stream>>>(es, ed, cnt, G, csr);

        for (int r = 0; r < NREL; ++r) {
            k_project1<<<N_NODES * F_HID / 256, 256, 0, stream>>>(
                x, W0 + (size_t)r * F_IN * F_HID, dout + (size_t)r * N_NODES, hproj);
            k_gather1<<<N_NODES * F_HID / 256, 256, 0, stream>>>(
                hproj, csr, G, dinv_in, h1acc, r * N_NODES, r == 0);
        }
        for (int r = 0; r < NREL; ++r) {
            k_project2<<<N_NODES * 32 / 256, 256, 0, stream>>>(
                h1acc, b0, Wmu + (size_t)r * F_HID * F_OUT,
                Wls + (size_t)r * F_HID * F_OUT, dout + (size_t)r * N_NODES, hproj);
            k_gather2<<<N_NODES * 32 / 256, 256, 0, stream>>>(
                hproj, csr, G, dinv_in, l2acc, r * N_NODES, r == 0);
        }
        k_finalize<<<N_NODES * F_OUT / 256, 256, 0, stream>>>(
            l2acc, bmu, bls, out + 2 * EP);
        k_scores<<<(2 * EP + 255) / 256, 256, 0, stream>>>(
            ps, pd, ns, nd, out + 2 * EP, out);
    } else {
        // ---------------- fallback: proven R7 atomic path ----------------
        float* dinv_out = wsf + ODINV_OUT;
        float* dinv_in  = wsf + ODINV_IN;
        float* h1acc    = wsf + OH1ACC;
        float* hproj    = wsf + OHPROJ;
        float* l2acc    = wsf + OL2ACC;

        hipMemsetAsync(dinv_out, 0, (size_t)2 * NRN * sizeof(float), stream);
        hipMemsetAsync(h1acc, 0, (size_t)N_NODES * F_HID * sizeof(float), stream);
        hipMemsetAsync(l2acc, 0, (size_t)N_NODES * 32 * sizeof(float), stream);

        k_degrees<<<dim3(E_PER / 256, NREL), 256, 0, stream>>>(es, ed, dinv_out, dinv_in);
        k_finalize_deg<<<(2 * NRN + 255) / 256, 256, 0, stream>>>(wsf);

        for (int r = 0; r < NREL; ++r) {
            k_project1<<<N_NODES * F_HID / 256, 256, 0, stream>>>(
                x, W0 + (size_t)r * F_IN * F_HID, dinv_out + (size_t)r * N_NODES, hproj);
            k_scatter1<<<E_PER / 4, 256, 0, stream>>>(
                hproj, es + (size_t)r * E_PER, ed + (size_t)r * E_PER,
                dinv_in + (size_t)r * N_NODES, h1acc);
        }
        for (int r = 0; r < NREL; ++r) {
            k_project2<<<N_NODES * 32 / 256, 256, 0, stream>>>(
                h1acc, b0, Wmu + (size_t)r * F_HID * F_OUT,
                Wls + (size_t)r * F_HID * F_OUT, dinv_out + (size_t)r * N_NODES, hproj);
            k_scatter2<<<E_PER / 8, 256, 0, stream>>>(
                hproj, es + (size_t)r * E_PER, ed + (size_t)r * E_PER,
                dinv_in + (size_t)r * N_NODES, l2acc);
        }
        k_finalize<<<N_NODES * F_OUT / 256, 256, 0, stream>>>(
            l2acc, bmu, bls, out + 2 * EP);
        k_scores<<<(2 * EP + 255) / 256, 256, 0, stream>>>(
            ps, pd, ns, nd, out + 2 * EP, out);
    }
}

// Round 9
// 1690.461 us; speedup vs baseline: 1.5919x; 1.1168x over previous
//
#include <hip/hip_runtime.h>
#include <math.h>

#define N_NODES 100000
#define NREL 3
#define E_PER 1600000
#define E_TOT 4800000
#define EP 500000
#define F_IN 128
#define F_HID 64
#define F_OUT 16
#define NRN 300000   // NREL*N_NODES

// ---------------- CSR-path ws layout (element offsets) ----------------
// e_slot (int, 4.8M) aliases hproj (float, 6.4M): e_slot dead after k_fill,
// hproj born at k_project1 (strictly later on the same stream).
#define OFF_DOUT    0           // 300000 f: out-deg hist -> rsqrt in place
#define OFF_DINVIN  300000      // 300000 f
#define OFF_CNT     600000      // 300000 i: in-deg counts
#define OFF_G       900000      // 300000 i: CSR offsets (exclusive prefix)
#define OFF_BSUM    1200000     // 1024 i
#define OFF_CSR     1201024     // 4800000 i: dst-sorted src indices
#define OFF_ESLOT   6001024     // 4800000 i  (alias w/ hproj)
#define OFF_HPROJ   6001024     // 6400000 f
#define OFF_H1      12401024    // 6400000 f
#define OFF_L2      18801024    // 3200000 f
#define WS_NEED_CSR 22001024    // 88.0 MB — proven to fit in R8
// ---------------- fallback (R7 atomic-scatter) layout ----------------
#define ODINV_OUT 0
#define ODINV_IN  300000
#define OH1ACC    600000
#define OHPROJ    7000000
#define OL2ACC    13400000

__device__ __forceinline__ float atomAddF(float* p, float v) {
    return unsafeAtomicAdd(p, v);  // proven identical to CAS path (R3 vs R4)
}

__device__ __forceinline__ unsigned rotl32(unsigned x, unsigned d) {
    return (x << d) | (x >> (32u - d));
}

// jax.random.normal(key(42), (100000,16)) — partitionable threefry2x32,
// counter (0,i), key (0,42), XOR-folded output words. Verified PASS in R7/R8.
__device__ float jax_noise(unsigned i) {
    const unsigned ks0 = 0u, ks1 = 42u;
    const unsigned ks2 = ks0 ^ ks1 ^ 0x1BD11BDAu;
    unsigned x0 = 0u + ks0;
    unsigned x1 = i + ks1;
#define TFR(r) { x0 += x1; x1 = rotl32(x1, r); x1 ^= x0; }
    TFR(13) TFR(15) TFR(26) TFR(6)
    x0 += ks1; x1 += ks2 + 1u;
    TFR(17) TFR(29) TFR(16) TFR(24)
    x0 += ks2; x1 += ks0 + 2u;
    TFR(13) TFR(15) TFR(26) TFR(6)
    x0 += ks0; x1 += ks1 + 3u;
    TFR(17) TFR(29) TFR(16) TFR(24)
    x0 += ks1; x1 += ks2 + 4u;
    TFR(13) TFR(15) TFR(26) TFR(6)
    x0 += ks2; x1 += ks0 + 5u;
#undef TFR
    const unsigned bits = x0 ^ x1;
    float f = __uint_as_float((bits >> 9) | 0x3f800000u) - 1.0f;
    const float lo = -0.99999994f;
    float u = fmaxf(lo, f * 2.0f + lo);
    float w = -log1pf(-u * u);
    float p;
    if (w < 5.0f) {
        w -= 2.5f;
        p = 2.81022636e-08f;
        p = fmaf(p, w, 3.43273939e-07f);
        p = fmaf(p, w, -3.5233877e-06f);
        p = fmaf(p, w, -4.39150654e-06f);
        p = fmaf(p, w, 0.00021858087f);
        p = fmaf(p, w, -0.00125372503f);
        p = fmaf(p, w, -0.00417768164f);
        p = fmaf(p, w, 0.246640727f);
        p = fmaf(p, w, 1.50140941f);
    } else {
        w = sqrtf(w) - 3.0f;
        p = -0.000200214257f;
        p = fmaf(p, w, 0.000100950558f);
        p = fmaf(p, w, 0.00134934322f);
        p = fmaf(p, w, -0.00367342844f);
        p = fmaf(p, w, 0.00573950773f);
        p = fmaf(p, w, -0.0076224613f);
        p = fmaf(p, w, 0.00943887047f);
        p = fmaf(p, w, 1.00167406f);
        p = fmaf(p, w, 2.83297682f);
    }
    return 1.41421356237f * (p * u);
}

// ---------------------------------------------------------------- CSR path
// in-deg counts (slot saved -> cursor-free fill) + out-deg float histogram.
__global__ __launch_bounds__(256) void k_hist(const int* __restrict__ es,
                                              const int* __restrict__ ed,
                                              int* __restrict__ cnt,
                                              float* __restrict__ dout,
                                              int* __restrict__ eslot) {
    const int r = blockIdx.y;
    const int e = blockIdx.x * 256 + threadIdx.x;
    const int gid = r * E_PER + e;
    const int s = es[gid];
    const int d = ed[gid];
    eslot[gid] = atomicAdd(&cnt[r * N_NODES + d], 1);
    atomAddF(&dout[r * N_NODES + s], 1.0f);
}

// block sums over 1024-element spans of cnt. grid 294 x 256.
__global__ __launch_bounds__(256) void k_scanA(const int* __restrict__ cnt,
                                               int* __restrict__ bsum) {
    __shared__ int red[256];
    const int base = blockIdx.x * 1024 + threadIdx.x * 4;
    int s = 0;
#pragma unroll
    for (int q = 0; q < 4; ++q) {
        const int i = base + q;
        s += (i < NRN) ? cnt[i] : 0;
    }
    red[threadIdx.x] = s;
    __syncthreads();
    for (int w = 128; w > 0; w >>= 1) {
        if (threadIdx.x < w) red[threadIdx.x] += red[threadIdx.x + w];
        __syncthreads();
    }
    if (threadIdx.x == 0) bsum[blockIdx.x] = red[0];
}

// exclusive scan of 294 block sums (in place). 1 block x 512.
__global__ __launch_bounds__(512) void k_scanB(int* __restrict__ bsum) {
    __shared__ int sc[512];
    const int t = threadIdx.x;
    sc[t] = (t < 294) ? bsum[t] : 0;
    __syncthreads();
    for (int o = 1; o < 512; o <<= 1) {
        const int v = (t >= o) ? sc[t - o] : 0;
        __syncthreads();
        sc[t] += v;
        __syncthreads();
    }
    bsum[t] = (t > 0) ? sc[t - 1] : 0;
}

// add-back: G = global exclusive prefix; dinv_in = rsqrt(max(cnt,1));
// dout := rsqrt(max(dout,1)) in place.
__global__ __launch_bounds__(256) void k_scanC(const int* __restrict__ cnt,
                                               const int* __restrict__ bsum,
                                               int* __restrict__ G,
                                               float* __restrict__ dinv_in,
                                               float* __restrict__ dout) {
    __shared__ int sc[256];
    const int t = threadIdx.x;
    const int base = blockIdx.x * 1024 + t * 4;
    int v[4];
    int ts = 0;
#pragma unroll
    for (int q = 0; q < 4; ++q) {
        const int i = base + q;
        v[q] = (i < NRN) ? cnt[i] : 0;
        ts += v[q];
    }
    sc[t] = ts;
    __syncthreads();
    for (int o = 1; o < 256; o <<= 1) {
        const int x = (t >= o) ? sc[t - o] : 0;
        __syncthreads();
        sc[t] += x;
        __syncthreads();
    }
    int run = bsum[blockIdx.x] + ((t > 0) ? sc[t - 1] : 0);
#pragma unroll
    for (int q = 0; q < 4; ++q) {
        const int i = base + q;
        if (i < NRN) {
            G[i] = run;
            dinv_in[i] = rsqrtf((float)max(v[q], 1));
            dout[i] = rsqrtf(fmaxf(dout[i], 1.0f));
        }
        run += v[q];
    }
}

// atomic-free dst-sorted CSR fill (slot precomputed by k_hist).
__global__ __launch_bounds__(256) void k_fill(const int* __restrict__ es,
                                              const int* __restrict__ ed,
                                              const int* __restrict__ eslot,
                                              const int* __restrict__ G,
                                              int* __restrict__ csr) {
    const int r = blockIdx.y;
    const int e = blockIdx.x * 256 + threadIdx.x;
    const int gid = r * E_PER + e;
    const int s = es[gid];
    const int d = ed[gid];
    const int idx = r * N_NODES + d;
    csr[G[idx] + eslot[gid]] = s;
}

// atomic-free aggregation, 64 feats: one wave per dst node.
__global__ __launch_bounds__(256) void k_gather1(const float* __restrict__ hp,
                                                 const int* __restrict__ csr,
                                                 const int* __restrict__ G,
                                                 const float* __restrict__ dinv,
                                                 float* __restrict__ h1,
                                                 int rbase, int first) {
    const int t = blockIdx.x * 256 + threadIdx.x;
    const int n = t >> 6;
    const int lane = t & 63;
    const int idx = rbase + n;
    const int off0 = G[idx];
    const int off1 = (idx == NRN - 1) ? E_TOT : G[idx + 1];
    float sum = 0.f;
    for (int base = off0; base < off1; base += 64) {
        int m = off1 - base;
        if (m > 64) m = 64;
        const int sv = (lane < m) ? csr[base + lane] : 0;
        for (int j = 0; j < m; ++j) {
            const int s = __shfl(sv, j);
            sum += hp[s * F_HID + lane];
        }
    }
    const float v = dinv[idx] * sum;
    if (first) h1[n * F_HID + lane] = v;
    else       h1[n * F_HID + lane] += v;
}

// 32-feat aggregation for relations 0..1 (accumulate into l2acc).
__global__ __launch_bounds__(256) void k_gather2(const float* __restrict__ hp,
                                                 const int* __restrict__ csr,
                                                 const int* __restrict__ G,
                                                 const float* __restrict__ dinv,
                                                 float* __restrict__ l2,
                                                 int rbase, int first) {
    const int t = blockIdx.x * 256 + threadIdx.x;
    const int n = t >> 5;
    const int c = t & 31;
    const int idx = rbase + n;
    const int off0 = G[idx];
    const int off1 = (idx == NRN - 1) ? E_TOT : G[idx + 1];
    float sum = 0.f;
    for (int base = off0; base < off1; base += 32) {
        int m = off1 - base;
        if (m > 32) m = 32;
        const int sv = (c < m) ? csr[base + c] : 0;
        for (int j = 0; j < m; ++j) {
            const int s = __shfl(sv, j, 32);
            sum += hp[s * 32 + c];
        }
    }
    const float v = dinv[idx] * sum;
    if (first) l2[n * 32 + c] = v;
    else       l2[n * 32 + c] += v;
}

// last relation's gather2 fused with the VGAE epilogue: h = mu + z*exp(ls),
// written straight to out (no finalize pass, no l2 write-back).
__global__ __launch_bounds__(256) void k_gather2_fin(const float* __restrict__ hp,
                                                     const int* __restrict__ csr,
                                                     const int* __restrict__ G,
                                                     const float* __restrict__ dinv,
                                                     const float* __restrict__ l2,
                                                     const float* __restrict__ bmu,
                                                     const float* __restrict__ bls,
                                                     float* __restrict__ outh,
                                                     int rbase) {
    const int t = blockIdx.x * 256 + threadIdx.x;
    const int n = t >> 5;
    const int c = t & 31;
    const int idx = rbase + n;
    const int off0 = G[idx];
    const int off1 = (idx == NRN - 1) ? E_TOT : G[idx + 1];
    float sum = 0.f;
    for (int base = off0; base < off1; base += 32) {
        int m = off1 - base;
        if (m > 32) m = 32;
        const int sv = (c < m) ? csr[base + c] : 0;
        for (int j = 0; j < m; ++j) {
            const int s = __shfl(sv, j, 32);
            sum += hp[s * 32 + c];
        }
    }
    const float v = l2[n * 32 + c] + dinv[idx] * sum;  // total over 3 relations
    const float vo = __shfl(v, c + 16, 32);            // partner word (ls for c<16)
    if (c < 16) {
        const float mean = v + bmu[c] + bmu[16 + c] + bmu[32 + c];
        const float lstd = vo + bls[c] + bls[16 + c] + bls[32 + c];
        const float z = jax_noise((unsigned)(n * 16 + c));
        outh[n * 16 + c] = mean + z * expf(lstd);
    }
}

// ------------------------------------------------------ projections
// grid-stride: W loaded into LDS once per block (1024 blocks).
__global__ __launch_bounds__(256) void k_project1(const float* __restrict__ x,
                                                  const float* __restrict__ W,
                                                  const float* __restrict__ dinv,
                                                  float* __restrict__ out) {
    __shared__ float ws[F_IN * F_HID];
    for (int i = threadIdx.x; i < F_IN * F_HID; i += 256) ws[i] = W[i];
    __syncthreads();
    for (int t = blockIdx.x * 256 + threadIdx.x; t < N_NODES * F_HID;
         t += gridDim.x * 256) {
        const int n = t >> 6;
        const int c = t & 63;
        const float* xr = x + (size_t)n * F_IN;
        float acc = 0.f;
#pragma unroll 16
        for (int k = 0; k < F_IN; ++k) acc = fmaf(xr[k], ws[k * F_HID + c], acc);
        out[t] = acc * dinv[n];
    }
}

__global__ __launch_bounds__(256) void k_project2(const float* __restrict__ h1,
                                                  const float* __restrict__ b0,
                                                  const float* __restrict__ Wmu,
                                                  const float* __restrict__ Wls,
                                                  const float* __restrict__ dinv,
                                                  float* __restrict__ out) {
    __shared__ float ws[F_HID * 32];
    __shared__ float bs[F_HID];
    for (int i = threadIdx.x; i < F_HID * 32; i += 256) {
        const int k = i >> 5, c = i & 31;
        ws[i] = (c < 16) ? Wmu[k * 16 + c] : Wls[k * 16 + (c - 16)];
    }
    if (threadIdx.x < F_HID)
        bs[threadIdx.x] = b0[threadIdx.x] + b0[64 + threadIdx.x] + b0[128 + threadIdx.x];
    __syncthreads();
    for (int t = blockIdx.x * 256 + threadIdx.x; t < N_NODES * 32;
         t += gridDim.x * 256) {
        const int n = t >> 5;
        const int c = t & 31;
        const float* hr = h1 + (size_t)n * F_HID;
        float acc = 0.f;
#pragma unroll 8
        for (int k = 0; k < F_HID; ++k) {
            const float v = fmaxf(hr[k] + bs[k], 0.f);
            acc = fmaf(v, ws[k * 32 + c], acc);
        }
        out[t] = acc * dinv[n];
    }
}

__global__ __launch_bounds__(256) void k_scores(const int* __restrict__ ps,
                                                const int* __restrict__ pd,
                                                const int* __restrict__ ns,
                                                const int* __restrict__ nd,
                                                const float* __restrict__ h,
                                                float* __restrict__ out) {
    const int i = blockIdx.x * 256 + threadIdx.x;
    if (i >= 2 * EP) return;
    const int j = (i < EP) ? i : i - EP;
    const int a = (i < EP) ? ps[j] : ns[j];
    const int b = (i < EP) ? pd[j] : nd[j];
    const float4* ha = (const float4*)(h + (size_t)a * 16);
    const float4* hb = (const float4*)(h + (size_t)b * 16);
    float s = 0.f;
#pragma unroll
    for (int q = 0; q < 4; ++q) {
        const float4 u = ha[q];
        const float4 v = hb[q];
        s += u.x * v.x + u.y * v.y + u.z * v.z + u.w * v.w;
    }
    out[i] = s;
}

// --------------------------------------------- fallback (R7 atomic-scatter)
__global__ __launch_bounds__(256) void k_degrees(const int* __restrict__ es,
                                                 const int* __restrict__ ed,
                                                 float* __restrict__ dout,
                                                 float* __restrict__ din) {
    const int r = blockIdx.y;
    const int e = blockIdx.x * 256 + threadIdx.x;
    const int s = es[r * E_PER + e];
    const int d = ed[r * E_PER + e];
    atomAddF(&dout[r * N_NODES + s], 1.0f);
    atomAddF(&din[r * N_NODES + d], 1.0f);
}

__global__ __launch_bounds__(256) void k_finalize_deg(float* __restrict__ d) {
    const int i = blockIdx.x * 256 + threadIdx.x;
    if (i < 2 * NRN) d[i] = 1.0f / sqrtf(fmaxf(d[i], 1.0f));
}

__global__ __launch_bounds__(256) void k_scatter1(const float* __restrict__ hp,
                                                  const int* __restrict__ es,
                                                  const int* __restrict__ ed,
                                                  const float* __restrict__ din,
                                                  float* __restrict__ acc) {
    const int t = blockIdx.x * 256 + threadIdx.x;
    const int e = t >> 6;
    const int lane = t & 63;
    const int s = es[e];
    const int d = ed[e];
    const float v = hp[s * F_HID + lane] * din[d];
    atomAddF(&acc[d * F_HID + lane], v);
}

__global__ __launch_bounds__(256) void k_scatter2(const float* __restrict__ hp,
                                                  const int* __restrict__ es,
                                                  const int* __restrict__ ed,
                                                  const float* __restrict__ din,
                                                  float* __restrict__ acc) {
    const int t = blockIdx.x * 256 + threadIdx.x;
    const int e = t >> 5;
    const int c = t & 31;
    const int s = es[e];
    const int d = ed[e];
    const float v = hp[s * 32 + c] * din[d];
    atomAddF(&acc[d * 32 + c], v);
}

__global__ __launch_bounds__(256) void k_finalize(const float* __restrict__ l2,
                                                  const float* __restrict__ bmu,
                                                  const float* __restrict__ bls,
                                                  float* __restrict__ outh) {
    const int i = blockIdx.x * 256 + threadIdx.x;
    const int n = i >> 4, c = i & 15;
    const float mean = l2[n * 32 + c] + bmu[c] + bmu[16 + c] + bmu[32 + c];
    const float lstd = l2[n * 32 + 16 + c] + bls[c] + bls[16 + c] + bls[32 + c];
    const float z = jax_noise((unsigned)i);
    outh[i] = mean + z * expf(lstd);
}

extern "C" void kernel_launch(void* const* d_in, const int* in_sizes, int n_in,
                              void* d_out, int out_size, void* d_ws, size_t ws_size,
                              hipStream_t stream) {
    const float* x   = (const float*)d_in[0];
    const float* W0  = (const float*)d_in[1];
    const float* b0  = (const float*)d_in[2];
    const float* Wmu = (const float*)d_in[3];
    const float* bmu = (const float*)d_in[4];
    const float* Wls = (const float*)d_in[5];
    const float* bls = (const float*)d_in[6];
    const int* es = (const int*)d_in[7];
    const int* ed = (const int*)d_in[8];
    const int* ps = (const int*)d_in[9];
    const int* pd = (const int*)d_in[10];
    const int* ns = (const int*)d_in[11];
    const int* nd = (const int*)d_in[12];
    float* out = (float*)d_out;
    float* wsf = (float*)d_ws;

    if (ws_size >= (size_t)WS_NEED_CSR * sizeof(float)) {
        // ---------------- CSR path ----------------
        float* dout    = wsf + OFF_DOUT;     // -> dinv_out after scanC
        float* dinv_in = wsf + OFF_DINVIN;
        int*   cnt     = (int*)(wsf + OFF_CNT);
        int*   G       = (int*)(wsf + OFF_G);
        int*   bsum    = (int*)(wsf + OFF_BSUM);
        int*   csr     = (int*)(wsf + OFF_CSR);
        int*   eslot   = (int*)(wsf + OFF_ESLOT);   // aliases hproj
        float* hproj   = wsf + OFF_HPROJ;
        float* h1acc   = wsf + OFF_H1;
        float* l2acc   = wsf + OFF_L2;

        hipMemsetAsync(dout, 0, (size_t)NRN * sizeof(float), stream);
        hipMemsetAsync(cnt, 0, (size_t)NRN * sizeof(int), stream);

        k_hist<<<dim3(E_PER / 256, NREL), 256, 0, stream>>>(es, ed, cnt, dout, eslot);
        k_scanA<<<294, 256, 0, stream>>>(cnt, bsum);
        k_scanB<<<1, 512, 0, stream>>>(bsum);
        k_scanC<<<294, 256, 0, stream>>>(cnt, bsum, G, dinv_in, dout);
        k_fill<<<dim3(E_PER / 256, NREL), 256, 0, stream>>>(es, ed, eslot, G, csr);

        for (int r = 0; r < NREL; ++r) {
            k_project1<<<1024, 256, 0, stream>>>(
                x, W0 + (size_t)r * F_IN * F_HID, dout + (size_t)r * N_NODES, hproj);
            k_gather1<<<N_NODES * F_HID / 256, 256, 0, stream>>>(
                hproj, csr, G, dinv_in, h1acc, r * N_NODES, r == 0);
        }
        for (int r = 0; r < NREL; ++r) {
            k_project2<<<512, 256, 0, stream>>>(
                h1acc, b0, Wmu + (size_t)r * F_HID * F_OUT,
                Wls + (size_t)r * F_HID * F_OUT, dout + (size_t)r * N_NODES, hproj);
            if (r < NREL - 1) {
                k_gather2<<<N_NODES * 32 / 256, 256, 0, stream>>>(
                    hproj, csr, G, dinv_in, l2acc, r * N_NODES, r == 0);
            } else {
                k_gather2_fin<<<N_NODES * 32 / 256, 256, 0, stream>>>(
                    hproj, csr, G, dinv_in, l2acc, bmu, bls, out + 2 * EP,
                    r * N_NODES);
            }
        }
        k_scores<<<(2 * EP + 255) / 256, 256, 0, stream>>>(
            ps, pd, ns, nd, out + 2 * EP, out);
    } else {
        // ---------------- fallback: proven R7 atomic path ----------------
        float* dinv_out = wsf + ODINV_OUT;
        float* dinv_in  = wsf + ODINV_IN;
        float* h1acc    = wsf + OH1ACC;
        float* hproj    = wsf + OHPROJ;
        float* l2acc    = wsf + OL2ACC;

        hipMemsetAsync(dinv_out, 0, (size_t)2 * NRN * sizeof(float), stream);
        hipMemsetAsync(h1acc, 0, (size_t)N_NODES * F_HID * sizeof(float), stream);
        hipMemsetAsync(l2acc, 0, (size_t)N_NODES * 32 * sizeof(float), stream);

        k_degrees<<<dim3(E_PER / 256, NREL), 256, 0, stream>>>(es, ed, dinv_out, dinv_in);
        k_finalize_deg<<<(2 * NRN + 255) / 256, 256, 0, stream>>>(wsf);

        for (int r = 0; r < NREL; ++r) {
            k_project1<<<1024, 256, 0, stream>>>(
                x, W0 + (size_t)r * F_IN * F_HID, dinv_out + (size_t)r * N_NODES, hproj);
            k_scatter1<<<E_PER / 4, 256, 0, stream>>>(
                hproj, es + (size_t)r * E_PER, ed + (size_t)r * E_PER,
                dinv_in + (size_t)r * N_NODES, h1acc);
        }
        for (int r = 0; r < NREL; ++r) {
            k_project2<<<512, 256, 0, stream>>>(
                h1acc, b0, Wmu + (size_t)r * F_HID * F_OUT,
                Wls + (size_t)r * F_HID * F_OUT, dinv_out + (size_t)r * N_NODES, hproj);
            k_scatter2<<<E_PER / 8, 256, 0, stream>>>(
                hproj, es + (size_t)r * E_PER, ed + (size_t)r * E_PER,
                dinv_in + (size_t)r * N_NODES, l2acc);
        }
        k_finalize<<<N_NODES * F_OUT / 256, 256, 0, stream>>>(
            l2acc, bmu, bls, out + 2 * EP);
        k_scores<<<(2 * EP + 255) / 256, 256, 0, stream>>>(
            ps, pd, ns, nd, out + 2 * EP, out);
    }
}

// Round 10
// 1600.016 us; speedup vs baseline: 1.6819x; 1.0565x over previous
//
#include <hip/hip_runtime.h>
#include <math.h>

#define N_NODES 100000
#define NREL 3
#define E_PER 1600000
#define E_TOT 4800000
#define EP 500000
#define F_IN 128
#define F_HID 64
#define F_OUT 16
#define NRN 300000   // NREL*N_NODES

// ---------------- CSR-path ws layout (element offsets) ----------------
// e_slot (int, 4.8M) aliases hproj (float, 6.4M): e_slot dead after k_fill,
// hproj born at k_project1 (strictly later on the same stream).
#define OFF_DOUT    0           // 300000 f: out-deg hist -> rsqrt in place
#define OFF_DINVIN  300000      // 300000 f
#define OFF_CNT     600000      // 300000 i: in-deg counts
#define OFF_G       900000      // 300000 i: CSR offsets (exclusive prefix)
#define OFF_BSUM    1200000     // 1024 i
#define OFF_CSR     1201024     // 4800000 i: dst-sorted src indices
#define OFF_ESLOT   6001024     // 4800000 i  (alias w/ hproj)
#define OFF_HPROJ   6001024     // 6400000 f
#define OFF_H1      12401024    // 6400000 f
#define OFF_L2      18801024    // 3200000 f
#define WS_NEED_CSR 22001024    // 88.0 MB — proven to fit (R8/R9)
// ---------------- fallback (R7 atomic-scatter) layout ----------------
#define ODINV_OUT 0
#define ODINV_IN  300000
#define OH1ACC    600000
#define OHPROJ    7000000
#define OL2ACC    13400000

__device__ __forceinline__ float atomAddF(float* p, float v) {
    return unsafeAtomicAdd(p, v);  // proven identical to CAS path (R3 vs R4)
}

__device__ __forceinline__ unsigned rotl32(unsigned x, unsigned d) {
    return (x << d) | (x >> (32u - d));
}

// jax.random.normal(key(42), (100000,16)) — partitionable threefry2x32,
// counter (0,i), key (0,42), XOR-folded output words. Verified PASS R7-R9.
__device__ float jax_noise(unsigned i) {
    const unsigned ks0 = 0u, ks1 = 42u;
    const unsigned ks2 = ks0 ^ ks1 ^ 0x1BD11BDAu;
    unsigned x0 = 0u + ks0;
    unsigned x1 = i + ks1;
#define TFR(r) { x0 += x1; x1 = rotl32(x1, r); x1 ^= x0; }
    TFR(13) TFR(15) TFR(26) TFR(6)
    x0 += ks1; x1 += ks2 + 1u;
    TFR(17) TFR(29) TFR(16) TFR(24)
    x0 += ks2; x1 += ks0 + 2u;
    TFR(13) TFR(15) TFR(26) TFR(6)
    x0 += ks0; x1 += ks1 + 3u;
    TFR(17) TFR(29) TFR(16) TFR(24)
    x0 += ks1; x1 += ks2 + 4u;
    TFR(13) TFR(15) TFR(26) TFR(6)
    x0 += ks2; x1 += ks0 + 5u;
#undef TFR
    const unsigned bits = x0 ^ x1;
    float f = __uint_as_float((bits >> 9) | 0x3f800000u) - 1.0f;
    const float lo = -0.99999994f;
    float u = fmaxf(lo, f * 2.0f + lo);
    float w = -log1pf(-u * u);
    float p;
    if (w < 5.0f) {
        w -= 2.5f;
        p = 2.81022636e-08f;
        p = fmaf(p, w, 3.43273939e-07f);
        p = fmaf(p, w, -3.5233877e-06f);
        p = fmaf(p, w, -4.39150654e-06f);
        p = fmaf(p, w, 0.00021858087f);
        p = fmaf(p, w, -0.00125372503f);
        p = fmaf(p, w, -0.00417768164f);
        p = fmaf(p, w, 0.246640727f);
        p = fmaf(p, w, 1.50140941f);
    } else {
        w = sqrtf(w) - 3.0f;
        p = -0.000200214257f;
        p = fmaf(p, w, 0.000100950558f);
        p = fmaf(p, w, 0.00134934322f);
        p = fmaf(p, w, -0.00367342844f);
        p = fmaf(p, w, 0.00573950773f);
        p = fmaf(p, w, -0.0076224613f);
        p = fmaf(p, w, 0.00943887047f);
        p = fmaf(p, w, 1.00167406f);
        p = fmaf(p, w, 2.83297682f);
    }
    return 1.41421356237f * (p * u);
}

// ---------------------------------------------------------------- CSR path
__global__ __launch_bounds__(256) void k_hist(const int* __restrict__ es,
                                              const int* __restrict__ ed,
                                              int* __restrict__ cnt,
                                              float* __restrict__ dout,
                                              int* __restrict__ eslot) {
    const int r = blockIdx.y;
    const int e = blockIdx.x * 256 + threadIdx.x;
    const int gid = r * E_PER + e;
    const int s = es[gid];
    const int d = ed[gid];
    eslot[gid] = atomicAdd(&cnt[r * N_NODES + d], 1);
    atomAddF(&dout[r * N_NODES + s], 1.0f);
}

__global__ __launch_bounds__(256) void k_scanA(const int* __restrict__ cnt,
                                               int* __restrict__ bsum) {
    __shared__ int red[256];
    const int base = blockIdx.x * 1024 + threadIdx.x * 4;
    int s = 0;
#pragma unroll
    for (int q = 0; q < 4; ++q) {
        const int i = base + q;
        s += (i < NRN) ? cnt[i] : 0;
    }
    red[threadIdx.x] = s;
    __syncthreads();
    for (int w = 128; w > 0; w >>= 1) {
        if (threadIdx.x < w) red[threadIdx.x] += red[threadIdx.x + w];
        __syncthreads();
    }
    if (threadIdx.x == 0) bsum[blockIdx.x] = red[0];
}

__global__ __launch_bounds__(512) void k_scanB(int* __restrict__ bsum) {
    __shared__ int sc[512];
    const int t = threadIdx.x;
    sc[t] = (t < 294) ? bsum[t] : 0;
    __syncthreads();
    for (int o = 1; o < 512; o <<= 1) {
        const int v = (t >= o) ? sc[t - o] : 0;
        __syncthreads();
        sc[t] += v;
        __syncthreads();
    }
    bsum[t] = (t > 0) ? sc[t - 1] : 0;
}

__global__ __launch_bounds__(256) void k_scanC(const int* __restrict__ cnt,
                                               const int* __restrict__ bsum,
                                               int* __restrict__ G,
                                               float* __restrict__ dinv_in,
                                               float* __restrict__ dout) {
    __shared__ int sc[256];
    const int t = threadIdx.x;
    const int base = blockIdx.x * 1024 + t * 4;
    int v[4];
    int ts = 0;
#pragma unroll
    for (int q = 0; q < 4; ++q) {
        const int i = base + q;
        v[q] = (i < NRN) ? cnt[i] : 0;
        ts += v[q];
    }
    sc[t] = ts;
    __syncthreads();
    for (int o = 1; o < 256; o <<= 1) {
        const int x = (t >= o) ? sc[t - o] : 0;
        __syncthreads();
        sc[t] += x;
        __syncthreads();
    }
    int run = bsum[blockIdx.x] + ((t > 0) ? sc[t - 1] : 0);
#pragma unroll
    for (int q = 0; q < 4; ++q) {
        const int i = base + q;
        if (i < NRN) {
            G[i] = run;
            dinv_in[i] = rsqrtf((float)max(v[q], 1));
            dout[i] = rsqrtf(fmaxf(dout[i], 1.0f));
        }
        run += v[q];
    }
}

__global__ __launch_bounds__(256) void k_fill(const int* __restrict__ es,
                                              const int* __restrict__ ed,
                                              const int* __restrict__ eslot,
                                              const int* __restrict__ G,
                                              int* __restrict__ csr) {
    const int r = blockIdx.y;
    const int e = blockIdx.x * 256 + threadIdx.x;
    const int gid = r * E_PER + e;
    const int s = es[gid];
    const int d = ed[gid];
    const int idx = r * N_NODES + d;
    csr[G[idx] + eslot[gid]] = s;
}

// gather 64 feats: one wave per dst node; 16 lanes x float4 cover features;
// 4 edges in flight per iteration (e4 = lane>>4); no wave divergence.
__global__ __launch_bounds__(256) void k_gather1(const float* __restrict__ hp,
                                                 const int* __restrict__ csr,
                                                 const int* __restrict__ G,
                                                 const float* __restrict__ dinv,
                                                 float* __restrict__ h1,
                                                 int rbase, int first) {
    const int node = (blockIdx.x * 256 + threadIdx.x) >> 6;
    const int lane = threadIdx.x & 63;
    const int l16 = lane & 15;
    const int e4 = lane >> 4;
    const int idx = rbase + node;
    const int off0 = G[idx];
    const int off1 = (idx == NRN - 1) ? E_TOT : G[idx + 1];
    float ax = 0.f, ay = 0.f, az = 0.f, aw = 0.f;
    for (int base = off0; base < off1; base += 64) {
        int m = off1 - base;
        if (m > 64) m = 64;
        const int sv = (lane < m) ? csr[base + lane] : 0;  // zeroed => safe hp[0] touch
        const int nq = (m + 3) >> 2;
        for (int q = 0; q < nq; ++q) {
            const int ei = q * 4 + e4;
            const int s = __shfl(sv, ei);
            const float4 v = *(const float4*)(hp + (size_t)s * F_HID + l16 * 4);
            const bool ok = ei < m;
            ax += ok ? v.x : 0.f;
            ay += ok ? v.y : 0.f;
            az += ok ? v.z : 0.f;
            aw += ok ? v.w : 0.f;
        }
    }
    ax += __shfl_xor(ax, 16); ay += __shfl_xor(ay, 16);
    az += __shfl_xor(az, 16); aw += __shfl_xor(aw, 16);
    ax += __shfl_xor(ax, 32); ay += __shfl_xor(ay, 32);
    az += __shfl_xor(az, 32); aw += __shfl_xor(aw, 32);
    if (lane < 16) {
        const float dv = dinv[idx];
        float4* dst = (float4*)(h1 + (size_t)node * F_HID) + l16;
        float4 o;
        if (first) {
            o.x = dv * ax; o.y = dv * ay; o.z = dv * az; o.w = dv * aw;
        } else {
            const float4 pr = *dst;
            o.x = pr.x + dv * ax; o.y = pr.y + dv * ay;
            o.z = pr.z + dv * az; o.w = pr.w + dv * aw;
        }
        *dst = o;
    }
}

// gather 32 feats (mu||ls): one wave per node; 8 lanes x float4; 8 edges/iter.
__global__ __launch_bounds__(256) void k_gather2(const float* __restrict__ hp,
                                                 const int* __restrict__ csr,
                                                 const int* __restrict__ G,
                                                 const float* __restrict__ dinv,
                                                 float* __restrict__ l2,
                                                 int rbase, int first) {
    const int node = (blockIdx.x * 256 + threadIdx.x) >> 6;
    const int lane = threadIdx.x & 63;
    const int l8 = lane & 7;
    const int e8 = lane >> 3;
    const int idx = rbase + node;
    const int off0 = G[idx];
    const int off1 = (idx == NRN - 1) ? E_TOT : G[idx + 1];
    float ax = 0.f, ay = 0.f, az = 0.f, aw = 0.f;
    for (int base = off0; base < off1; base += 64) {
        int m = off1 - base;
        if (m > 64) m = 64;
        const int sv = (lane < m) ? csr[base + lane] : 0;
        const int nq = (m + 7) >> 3;
        for (int q = 0; q < nq; ++q) {
            const int ei = q * 8 + e8;
            const int s = __shfl(sv, ei);
            const float4 v = *(const float4*)(hp + (size_t)s * 32 + l8 * 4);
            const bool ok = ei < m;
            ax += ok ? v.x : 0.f;
            ay += ok ? v.y : 0.f;
            az += ok ? v.z : 0.f;
            aw += ok ? v.w : 0.f;
        }
    }
    ax += __shfl_xor(ax, 8);  ay += __shfl_xor(ay, 8);
    az += __shfl_xor(az, 8);  aw += __shfl_xor(aw, 8);
    ax += __shfl_xor(ax, 16); ay += __shfl_xor(ay, 16);
    az += __shfl_xor(az, 16); aw += __shfl_xor(aw, 16);
    ax += __shfl_xor(ax, 32); ay += __shfl_xor(ay, 32);
    az += __shfl_xor(az, 32); aw += __shfl_xor(aw, 32);
    if (lane < 8) {
        const float dv = dinv[idx];
        float4* dst = (float4*)(l2 + (size_t)node * 32) + l8;
        float4 o;
        if (first) {
            o.x = dv * ax; o.y = dv * ay; o.z = dv * az; o.w = dv * aw;
        } else {
            const float4 pr = *dst;
            o.x = pr.x + dv * ax; o.y = pr.y + dv * ay;
            o.z = pr.z + dv * az; o.w = pr.w + dv * aw;
        }
        *dst = o;
    }
}

// last relation's 32-feat gather fused with VGAE epilogue -> out directly.
__global__ __launch_bounds__(256) void k_gather2_fin(const float* __restrict__ hp,
                                                     const int* __restrict__ csr,
                                                     const int* __restrict__ G,
                                                     const float* __restrict__ dinv,
                                                     const float* __restrict__ l2,
                                                     const float* __restrict__ bmu,
                                                     const float* __restrict__ bls,
                                                     float* __restrict__ outh,
                                                     int rbase) {
    const int node = (blockIdx.x * 256 + threadIdx.x) >> 6;
    const int lane = threadIdx.x & 63;
    const int l8 = lane & 7;
    const int e8 = lane >> 3;
    const int idx = rbase + node;
    const int off0 = G[idx];
    const int off1 = (idx == NRN - 1) ? E_TOT : G[idx + 1];
    float ax = 0.f, ay = 0.f, az = 0.f, aw = 0.f;
    for (int base = off0; base < off1; base += 64) {
        int m = off1 - base;
        if (m > 64) m = 64;
        const int sv = (lane < m) ? csr[base + lane] : 0;
        const int nq = (m + 7) >> 3;
        for (int q = 0; q < nq; ++q) {
            const int ei = q * 8 + e8;
            const int s = __shfl(sv, ei);
            const float4 v = *(const float4*)(hp + (size_t)s * 32 + l8 * 4);
            const bool ok = ei < m;
            ax += ok ? v.x : 0.f;
            ay += ok ? v.y : 0.f;
            az += ok ? v.z : 0.f;
            aw += ok ? v.w : 0.f;
        }
    }
    ax += __shfl_xor(ax, 8);  ay += __shfl_xor(ay, 8);
    az += __shfl_xor(az, 8);  aw += __shfl_xor(aw, 8);
    ax += __shfl_xor(ax, 16); ay += __shfl_xor(ay, 16);
    az += __shfl_xor(az, 16); aw += __shfl_xor(aw, 16);
    ax += __shfl_xor(ax, 32); ay += __shfl_xor(ay, 32);
    az += __shfl_xor(az, 32); aw += __shfl_xor(aw, 32);
    // lanes 0..7 hold the r=2 partial for quad c=l8*4; add prior relations.
    const float dv = dinv[idx];
    float vx = 0.f, vy = 0.f, vz = 0.f, vw = 0.f;
    if (lane < 8) {
        const float4 pr = *((const float4*)(l2 + (size_t)node * 32) + l8);
        vx = pr.x + dv * ax; vy = pr.y + dv * ay;
        vz = pr.z + dv * az; vw = pr.w + dv * aw;
    }
    // pair mu (lanes 0-3) with ls (lanes 4-7): partner quad at lane+4
    const float px = __shfl(vx, lane + 4);
    const float py = __shfl(vy, lane + 4);
    const float pz = __shfl(vz, lane + 4);
    const float pw = __shfl(vw, lane + 4);
    if (lane < 4) {
        const int c0 = lane * 4;
        float4 o;
        {
            const float mean = vx + bmu[c0] + bmu[16 + c0] + bmu[32 + c0];
            const float lstd = px + bls[c0] + bls[16 + c0] + bls[32 + c0];
            o.x = mean + jax_noise((unsigned)(node * 16 + c0)) * expf(lstd);
        }
        {
            const float mean = vy + bmu[c0 + 1] + bmu[17 + c0] + bmu[33 + c0];
            const float lstd = py + bls[c0 + 1] + bls[17 + c0] + bls[33 + c0];
            o.y = mean + jax_noise((unsigned)(node * 16 + c0 + 1)) * expf(lstd);
        }
        {
            const float mean = vz + bmu[c0 + 2] + bmu[18 + c0] + bmu[34 + c0];
            const float lstd = pz + bls[c0 + 2] + bls[18 + c0] + bls[34 + c0];
            o.z = mean + jax_noise((unsigned)(node * 16 + c0 + 2)) * expf(lstd);
        }
        {
            const float mean = vw + bmu[c0 + 3] + bmu[19 + c0] + bmu[35 + c0];
            const float lstd = pw + bls[c0 + 3] + bls[19 + c0] + bls[35 + c0];
            o.w = mean + jax_noise((unsigned)(node * 16 + c0 + 3)) * expf(lstd);
        }
        ((float4*)outh)[node * 4 + lane] = o;
    }
}

// ------------------------------------------------------ projections
__global__ __launch_bounds__(256) void k_project1(const float* __restrict__ x,
                                                  const float* __restrict__ W,
                                                  const float* __restrict__ dinv,
                                                  float* __restrict__ out) {
    __shared__ float ws[F_IN * F_HID];
    for (int i = threadIdx.x; i < F_IN * F_HID; i += 256) ws[i] = W[i];
    __syncthreads();
    for (int t = blockIdx.x * 256 + threadIdx.x; t < N_NODES * F_HID;
         t += gridDim.x * 256) {
        const int n = t >> 6;
        const int c = t & 63;
        const float* xr = x + (size_t)n * F_IN;
        float acc = 0.f;
#pragma unroll 16
        for (int k = 0; k < F_IN; ++k) acc = fmaf(xr[k], ws[k * F_HID + c], acc);
        out[t] = acc * dinv[n];
    }
}

__global__ __launch_bounds__(256) void k_project2(const float* __restrict__ h1,
                                                  const float* __restrict__ b0,
                                                  const float* __restrict__ Wmu,
                                                  const float* __restrict__ Wls,
                                                  const float* __restrict__ dinv,
                                                  float* __restrict__ out) {
    __shared__ float ws[F_HID * 32];
    __shared__ float bs[F_HID];
    for (int i = threadIdx.x; i < F_HID * 32; i += 256) {
        const int k = i >> 5, c = i & 31;
        ws[i] = (c < 16) ? Wmu[k * 16 + c] : Wls[k * 16 + (c - 16)];
    }
    if (threadIdx.x < F_HID)
        bs[threadIdx.x] = b0[threadIdx.x] + b0[64 + threadIdx.x] + b0[128 + threadIdx.x];
    __syncthreads();
    for (int t = blockIdx.x * 256 + threadIdx.x; t < N_NODES * 32;
         t += gridDim.x * 256) {
        const int n = t >> 5;
        const int c = t & 31;
        const float* hr = h1 + (size_t)n * F_HID;
        float acc = 0.f;
#pragma unroll 8
        for (int k = 0; k < F_HID; ++k) {
            const float v = fmaxf(hr[k] + bs[k], 0.f);
            acc = fmaf(v, ws[k * 32 + c], acc);
        }
        out[t] = acc * dinv[n];
    }
}

__global__ __launch_bounds__(256) void k_scores(const int* __restrict__ ps,
                                                const int* __restrict__ pd,
                                                const int* __restrict__ ns,
                                                const int* __restrict__ nd,
                                                const float* __restrict__ h,
                                                float* __restrict__ out) {
    const int i = blockIdx.x * 256 + threadIdx.x;
    if (i >= 2 * EP) return;
    const int j = (i < EP) ? i : i - EP;
    const int a = (i < EP) ? ps[j] : ns[j];
    const int b = (i < EP) ? pd[j] : nd[j];
    const float4* ha = (const float4*)(h + (size_t)a * 16);
    const float4* hb = (const float4*)(h + (size_t)b * 16);
    float s = 0.f;
#pragma unroll
    for (int q = 0; q < 4; ++q) {
        const float4 u = ha[q];
        const float4 v = hb[q];
        s += u.x * v.x + u.y * v.y + u.z * v.z + u.w * v.w;
    }
    out[i] = s;
}

// --------------------------------------------- fallback (R7 atomic-scatter)
__global__ __launch_bounds__(256) void k_degrees(const int* __restrict__ es,
                                                 const int* __restrict__ ed,
                                                 float* __restrict__ dout,
                                                 float* __restrict__ din) {
    const int r = blockIdx.y;
    const int e = blockIdx.x * 256 + threadIdx.x;
    const int s = es[r * E_PER + e];
    const int d = ed[r * E_PER + e];
    atomAddF(&dout[r * N_NODES + s], 1.0f);
    atomAddF(&din[r * N_NODES + d], 1.0f);
}

__global__ __launch_bounds__(256) void k_finalize_deg(float* __restrict__ d) {
    const int i = blockIdx.x * 256 + threadIdx.x;
    if (i < 2 * NRN) d[i] = 1.0f / sqrtf(fmaxf(d[i], 1.0f));
}

__global__ __launch_bounds__(256) void k_scatter1(const float* __restrict__ hp,
                                                  const int* __restrict__ es,
                                                  const int* __restrict__ ed,
                                                  const float* __restrict__ din,
                                                  float* __restrict__ acc) {
    const int t = blockIdx.x * 256 + threadIdx.x;
    const int e = t >> 6;
    const int lane = t & 63;
    const int s = es[e];
    const int d = ed[e];
    const float v = hp[s * F_HID + lane] * din[d];
    atomAddF(&acc[d * F_HID + lane], v);
}

__global__ __launch_bounds__(256) void k_scatter2(const float* __restrict__ hp,
                                                  const int* __restrict__ es,
                                                  const int* __restrict__ ed,
                                                  const float* __restrict__ din,
                                                  float* __restrict__ acc) {
    const int t = blockIdx.x * 256 + threadIdx.x;
    const int e = t >> 5;
    const int c = t & 31;
    const int s = es[e];
    const int d = ed[e];
    const float v = hp[s * 32 + c] * din[d];
    atomAddF(&acc[d * 32 + c], v);
}

__global__ __launch_bounds__(256) void k_finalize(const float* __restrict__ l2,
                                                  const float* __restrict__ bmu,
                                                  const float* __restrict__ bls,
                                                  float* __restrict__ outh) {
    const int i = blockIdx.x * 256 + threadIdx.x;
    const int n = i >> 4, c = i & 15;
    const float mean = l2[n * 32 + c] + bmu[c] + bmu[16 + c] + bmu[32 + c];
    const float lstd = l2[n * 32 + 16 + c] + bls[c] + bls[16 + c] + bls[32 + c];
    const float z = jax_noise((unsigned)i);
    outh[i] = mean + z * expf(lstd);
}

extern "C" void kernel_launch(void* const* d_in, const int* in_sizes, int n_in,
                              void* d_out, int out_size, void* d_ws, size_t ws_size,
                              hipStream_t stream) {
    const float* x   = (const float*)d_in[0];
    const float* W0  = (const float*)d_in[1];
    const float* b0  = (const float*)d_in[2];
    const float* Wmu = (const float*)d_in[3];
    const float* bmu = (const float*)d_in[4];
    const float* Wls = (const float*)d_in[5];
    const float* bls = (const float*)d_in[6];
    const int* es = (const int*)d_in[7];
    const int* ed = (const int*)d_in[8];
    const int* ps = (const int*)d_in[9];
    const int* pd = (const int*)d_in[10];
    const int* ns = (const int*)d_in[11];
    const int* nd = (const int*)d_in[12];
    float* out = (float*)d_out;
    float* wsf = (float*)d_ws;

    if (ws_size >= (size_t)WS_NEED_CSR * sizeof(float)) {
        // ---------------- CSR path ----------------
        float* dout    = wsf + OFF_DOUT;     // -> dinv_out after scanC
        float* dinv_in = wsf + OFF_DINVIN;
        int*   cnt     = (int*)(wsf + OFF_CNT);
        int*   G       = (int*)(wsf + OFF_G);
        int*   bsum    = (int*)(wsf + OFF_BSUM);
        int*   csr     = (int*)(wsf + OFF_CSR);
        int*   eslot   = (int*)(wsf + OFF_ESLOT);   // aliases hproj
        float* hproj   = wsf + OFF_HPROJ;
        float* h1acc   = wsf + OFF_H1;
        float* l2acc   = wsf + OFF_L2;

        hipMemsetAsync(dout, 0, (size_t)NRN * sizeof(float), stream);
        hipMemsetAsync(cnt, 0, (size_t)NRN * sizeof(int), stream);

        k_hist<<<dim3(E_PER / 256, NREL), 256, 0, stream>>>(es, ed, cnt, dout, eslot);
        k_scanA<<<294, 256, 0, stream>>>(cnt, bsum);
        k_scanB<<<1, 512, 0, stream>>>(bsum);
        k_scanC<<<294, 256, 0, stream>>>(cnt, bsum, G, dinv_in, dout);
        k_fill<<<dim3(E_PER / 256, NREL), 256, 0, stream>>>(es, ed, eslot, G, csr);

        for (int r = 0; r < NREL; ++r) {
            k_project1<<<1024, 256, 0, stream>>>(
                x, W0 + (size_t)r * F_IN * F_HID, dout + (size_t)r * N_NODES, hproj);
            k_gather1<<<N_NODES / 4, 256, 0, stream>>>(
                hproj, csr, G, dinv_in, h1acc, r * N_NODES, r == 0);
        }
        for (int r = 0; r < NREL; ++r) {
            k_project2<<<512, 256, 0, stream>>>(
                h1acc, b0, Wmu + (size_t)r * F_HID * F_OUT,
                Wls + (size_t)r * F_HID * F_OUT, dout + (size_t)r * N_NODES, hproj);
            if (r < NREL - 1) {
                k_gather2<<<N_NODES / 4, 256, 0, stream>>>(
                    hproj, csr, G, dinv_in, l2acc, r * N_NODES, r == 0);
            } else {
                k_gather2_fin<<<N_NODES / 4, 256, 0, stream>>>(
                    hproj, csr, G, dinv_in, l2acc, bmu, bls, out + 2 * EP,
                    r * N_NODES);
            }
        }
        k_scores<<<(2 * EP + 255) / 256, 256, 0, stream>>>(
            ps, pd, ns, nd, out + 2 * EP, out);
    } else {
        // ---------------- fallback: proven R7 atomic path ----------------
        float* dinv_out = wsf + ODINV_OUT;
        float* dinv_in  = wsf + ODINV_IN;
        float* h1acc    = wsf + OH1ACC;
        float* hproj    = wsf + OHPROJ;
        float* l2acc    = wsf + OL2ACC;

        hipMemsetAsync(dinv_out, 0, (size_t)2 * NRN * sizeof(float), stream);
        hipMemsetAsync(h1acc, 0, (size_t)N_NODES * F_HID * sizeof(float), stream);
        hipMemsetAsync(l2acc, 0, (size_t)N_NODES * 32 * sizeof(float), stream);

        k_degrees<<<dim3(E_PER / 256, NREL), 256, 0, stream>>>(es, ed, dinv_out, dinv_in);
        k_finalize_deg<<<(2 * NRN + 255) / 256, 256, 0, stream>>>(wsf);

        for (int r = 0; r < NREL; ++r) {
            k_project1<<<1024, 256, 0, stream>>>(
                x, W0 + (size_t)r * F_IN * F_HID, dinv_out + (size_t)r * N_NODES, hproj);
            k_scatter1<<<E_PER / 4, 256, 0, stream>>>(
                hproj, es + (size_t)r * E_PER, ed + (size_t)r * E_PER,
                dinv_in + (size_t)r * N_NODES, h1acc);
        }
        for (int r = 0; r < NREL; ++r) {
            k_project2<<<512, 256, 0, stream>>>(
                h1acc, b0, Wmu + (size_t)r * F_HID * F_OUT,
                Wls + (size_t)r * F_HID * F_OUT, dinv_out + (size_t)r * N_NODES, hproj);
            k_scatter2<<<E_PER / 8, 256, 0, stream>>>(
                hproj, es + (size_t)r * E_PER, ed + (size_t)r * E_PER,
                dinv_in + (size_t)r * N_NODES, l2acc);
        }
        k_finalize<<<N_NODES * F_OUT / 256, 256, 0, stream>>>(
            l2acc, bmu, bls, out + 2 * EP);
        k_scores<<<(2 * EP + 255) / 256, 256, 0, stream>>>(
            ps, pd, ns, nd, out + 2 * EP, out);
    }
}

// Round 11
// 1558.670 us; speedup vs baseline: 1.7265x; 1.0265x over previous
//
#include <hip/hip_runtime.h>
#include <math.h>

#define N_NODES 100000
#define NREL 3
#define E_PER 1600000
#define E_TOT 4800000
#define EP 500000
#define F_IN 128
#define F_HID 64
#define F_OUT 16
#define NRN 300000   // NREL*N_NODES

// two-level histogram params
#define NSEG 7
#define SEGSZ 16000          // 62.5 KB static LDS, 2 blocks/CU
#define NBLK 16
#define CHUNK (E_PER / NBLK) // 100000 edges/block

// ---------------- CSR-path ws layout (element offsets) ----------------
#define OFF_DOUT    0           // 300000: int counts -> float rsqrt in place
#define OFF_DINVIN  300000      // 300000 f
#define OFF_CNT     600000      // 300000 i: in-deg counts
#define OFF_G       900000      // 300000 i: CSR offsets (exclusive prefix)
#define OFF_BSUM    1200000     // 1024 i
#define OFF_CSR     1201024     // 4800000 i: dst-sorted src indices
#define OFF_ESLOT   6001024     // 4800000 i  (alias w/ hproj)
#define OFF_HPROJ   6001024     // 6400000 f
#define OFF_H1      12401024    // 6400000 f
#define OFF_L2      18801024    // 3200000 f
#define WS_NEED_CSR 22001024    // 88.0 MB — proven to fit (R8-R10)
// ---------------- fallback (R7 atomic-scatter) layout ----------------
#define ODINV_OUT 0
#define ODINV_IN  300000
#define OH1ACC    600000
#define OHPROJ    7000000
#define OL2ACC    13400000

__device__ __forceinline__ float atomAddF(float* p, float v) {
    return unsafeAtomicAdd(p, v);
}

__device__ __forceinline__ unsigned rotl32(unsigned x, unsigned d) {
    return (x << d) | (x >> (32u - d));
}

// jax.random.normal(key(42), (100000,16)) — partitionable threefry2x32,
// counter (0,i), key (0,42), XOR-folded output words. Verified PASS R7-R10.
__device__ float jax_noise(unsigned i) {
    const unsigned ks0 = 0u, ks1 = 42u;
    const unsigned ks2 = ks0 ^ ks1 ^ 0x1BD11BDAu;
    unsigned x0 = 0u + ks0;
    unsigned x1 = i + ks1;
#define TFR(r) { x0 += x1; x1 = rotl32(x1, r); x1 ^= x0; }
    TFR(13) TFR(15) TFR(26) TFR(6)
    x0 += ks1; x1 += ks2 + 1u;
    TFR(17) TFR(29) TFR(16) TFR(24)
    x0 += ks2; x1 += ks0 + 2u;
    TFR(13) TFR(15) TFR(26) TFR(6)
    x0 += ks0; x1 += ks1 + 3u;
    TFR(17) TFR(29) TFR(16) TFR(24)
    x0 += ks1; x1 += ks2 + 4u;
    TFR(13) TFR(15) TFR(26) TFR(6)
    x0 += ks2; x1 += ks0 + 5u;
#undef TFR
    const unsigned bits = x0 ^ x1;
    float f = __uint_as_float((bits >> 9) | 0x3f800000u) - 1.0f;
    const float lo = -0.99999994f;
    float u = fmaxf(lo, f * 2.0f + lo);
    float w = -log1pf(-u * u);
    float p;
    if (w < 5.0f) {
        w -= 2.5f;
        p = 2.81022636e-08f;
        p = fmaf(p, w, 3.43273939e-07f);
        p = fmaf(p, w, -3.5233877e-06f);
        p = fmaf(p, w, -4.39150654e-06f);
        p = fmaf(p, w, 0.00021858087f);
        p = fmaf(p, w, -0.00125372503f);
        p = fmaf(p, w, -0.00417768164f);
        p = fmaf(p, w, 0.246640727f);
        p = fmaf(p, w, 1.50140941f);
    } else {
        w = sqrtf(w) - 3.0f;
        p = -0.000200214257f;
        p = fmaf(p, w, 0.000100950558f);
        p = fmaf(p, w, 0.00134934322f);
        p = fmaf(p, w, -0.00367342844f);
        p = fmaf(p, w, 0.00573950773f);
        p = fmaf(p, w, -0.0076224613f);
        p = fmaf(p, w, 0.00943887047f);
        p = fmaf(p, w, 1.00167406f);
        p = fmaf(p, w, 2.83297682f);
    }
    return 1.41421356237f * (p * u);
}

// ------------------------------------------------------ two-level histograms
// in-degree counts + per-edge CSR slot, LDS-privatized.
// grid (NBLK, NSEG, NREL) x 256; 62.5 KB LDS.
__global__ __launch_bounds__(256) void k_histin(const int* __restrict__ ed,
                                                int* __restrict__ cnt,
                                                int* __restrict__ eslot) {
    __shared__ int lds[SEGSZ];
    const int r = blockIdx.z, g = blockIdx.y, b = blockIdx.x;
    const int lo = g * SEGSZ;
    const int hi = min(lo + SEGSZ, N_NODES);
    const int nbins = hi - lo;
    for (int i = threadIdx.x; i < nbins; i += 256) lds[i] = 0;
    __syncthreads();
    const int e0 = r * E_PER + b * CHUNK;
    const int e1 = e0 + CHUNK;
    // phase 1: private count
    for (int e = e0 + threadIdx.x; e < e1; e += 256) {
        const int d = ed[e];
        if (d >= lo && d < hi) atomicAdd(&lds[d - lo], 1);
    }
    __syncthreads();
    // phase 2: flush; fetch-add return = this block's exclusive base per bin
    for (int i = threadIdx.x; i < nbins; i += 256) {
        const int c = lds[i];
        lds[i] = c ? atomicAdd(&cnt[r * N_NODES + lo + i], c) : 0;
    }
    __syncthreads();
    // phase 3: final slot = LDS fetch-add from base (coalesced eslot write)
    for (int e = e0 + threadIdx.x; e < e1; e += 256) {
        const int d = ed[e];
        if (d >= lo && d < hi) eslot[e] = atomicAdd(&lds[d - lo], 1);
    }
}

// out-degree int counts, LDS-privatized (no slots).
__global__ __launch_bounds__(256) void k_histout(const int* __restrict__ es,
                                                 int* __restrict__ dout) {
    __shared__ int lds[SEGSZ];
    const int r = blockIdx.z, g = blockIdx.y, b = blockIdx.x;
    const int lo = g * SEGSZ;
    const int hi = min(lo + SEGSZ, N_NODES);
    const int nbins = hi - lo;
    for (int i = threadIdx.x; i < nbins; i += 256) lds[i] = 0;
    __syncthreads();
    const int e0 = r * E_PER + b * CHUNK;
    const int e1 = e0 + CHUNK;
    for (int e = e0 + threadIdx.x; e < e1; e += 256) {
        const int s = es[e];
        if (s >= lo && s < hi) atomicAdd(&lds[s - lo], 1);
    }
    __syncthreads();
    for (int i = threadIdx.x; i < nbins; i += 256) {
        const int c = lds[i];
        if (c) atomicAdd(&dout[r * N_NODES + lo + i], c);
    }
}

__global__ __launch_bounds__(256) void k_scanA(const int* __restrict__ cnt,
                                               int* __restrict__ bsum) {
    __shared__ int red[256];
    const int base = blockIdx.x * 1024 + threadIdx.x * 4;
    int s = 0;
#pragma unroll
    for (int q = 0; q < 4; ++q) {
        const int i = base + q;
        s += (i < NRN) ? cnt[i] : 0;
    }
    red[threadIdx.x] = s;
    __syncthreads();
    for (int w = 128; w > 0; w >>= 1) {
        if (threadIdx.x < w) red[threadIdx.x] += red[threadIdx.x + w];
        __syncthreads();
    }
    if (threadIdx.x == 0) bsum[blockIdx.x] = red[0];
}

__global__ __launch_bounds__(512) void k_scanB(int* __restrict__ bsum) {
    __shared__ int sc[512];
    const int t = threadIdx.x;
    sc[t] = (t < 294) ? bsum[t] : 0;
    __syncthreads();
    for (int o = 1; o < 512; o <<= 1) {
        const int v = (t >= o) ? sc[t - o] : 0;
        __syncthreads();
        sc[t] += v;
        __syncthreads();
    }
    bsum[t] = (t > 0) ? sc[t - 1] : 0;
}

// G = exclusive prefix; dinv_in = rsqrt(max(cnt,1));
// doutc: int counts -> float rsqrt written in place (same thread, same elem).
__global__ __launch_bounds__(256) void k_scanC(const int* __restrict__ cnt,
                                               const int* __restrict__ bsum,
                                               int* __restrict__ G,
                                               float* __restrict__ dinv_in,
                                               int* doutc) {
    __shared__ int sc[256];
    const int t = threadIdx.x;
    const int base = blockIdx.x * 1024 + t * 4;
    int v[4];
    int ts = 0;
#pragma unroll
    for (int q = 0; q < 4; ++q) {
        const int i = base + q;
        v[q] = (i < NRN) ? cnt[i] : 0;
        ts += v[q];
    }
    sc[t] = ts;
    __syncthreads();
    for (int o = 1; o < 256; o <<= 1) {
        const int x = (t >= o) ? sc[t - o] : 0;
        __syncthreads();
        sc[t] += x;
        __syncthreads();
    }
    int run = bsum[blockIdx.x] + ((t > 0) ? sc[t - 1] : 0);
#pragma unroll
    for (int q = 0; q < 4; ++q) {
        const int i = base + q;
        if (i < NRN) {
            G[i] = run;
            dinv_in[i] = rsqrtf((float)max(v[q], 1));
            const int oc = doutc[i];
            ((float*)doutc)[i] = rsqrtf((float)max(oc, 1));
        }
        run += v[q];
    }
}

__global__ __launch_bounds__(256) void k_fill(const int* __restrict__ es,
                                              const int* __restrict__ ed,
                                              const int* __restrict__ eslot,
                                              const int* __restrict__ G,
                                              int* __restrict__ csr) {
    const int r = blockIdx.y;
    const int e = blockIdx.x * 256 + threadIdx.x;
    const int gid = r * E_PER + e;
    const int s = es[gid];
    const int d = ed[gid];
    const int idx = r * N_NODES + d;
    csr[G[idx] + eslot[gid]] = s;
}

// gather 64 feats: one wave per dst node; 16 lanes x float4; 4 edges/iter.
__global__ __launch_bounds__(256) void k_gather1(const float* __restrict__ hp,
                                                 const int* __restrict__ csr,
                                                 const int* __restrict__ G,
                                                 const float* __restrict__ dinv,
                                                 float* __restrict__ h1,
                                                 int rbase, int first) {
    const int node = (blockIdx.x * 256 + threadIdx.x) >> 6;
    const int lane = threadIdx.x & 63;
    const int l16 = lane & 15;
    const int e4 = lane >> 4;
    const int idx = rbase + node;
    const int off0 = G[idx];
    const int off1 = (idx == NRN - 1) ? E_TOT : G[idx + 1];
    float ax = 0.f, ay = 0.f, az = 0.f, aw = 0.f;
    for (int base = off0; base < off1; base += 64) {
        int m = off1 - base;
        if (m > 64) m = 64;
        const int sv = (lane < m) ? csr[base + lane] : 0;
        const int nq = (m + 3) >> 2;
        for (int q = 0; q < nq; ++q) {
            const int ei = q * 4 + e4;
            const int s = __shfl(sv, ei);
            const float4 v = *(const float4*)(hp + (size_t)s * F_HID + l16 * 4);
            const bool ok = ei < m;
            ax += ok ? v.x : 0.f;
            ay += ok ? v.y : 0.f;
            az += ok ? v.z : 0.f;
            aw += ok ? v.w : 0.f;
        }
    }
    ax += __shfl_xor(ax, 16); ay += __shfl_xor(ay, 16);
    az += __shfl_xor(az, 16); aw += __shfl_xor(aw, 16);
    ax += __shfl_xor(ax, 32); ay += __shfl_xor(ay, 32);
    az += __shfl_xor(az, 32); aw += __shfl_xor(aw, 32);
    if (lane < 16) {
        const float dv = dinv[idx];
        float4* dst = (float4*)(h1 + (size_t)node * F_HID) + l16;
        float4 o;
        if (first) {
            o.x = dv * ax; o.y = dv * ay; o.z = dv * az; o.w = dv * aw;
        } else {
            const float4 pr = *dst;
            o.x = pr.x + dv * ax; o.y = pr.y + dv * ay;
            o.z = pr.z + dv * az; o.w = pr.w + dv * aw;
        }
        *dst = o;
    }
}

// gather 32 feats (mu||ls): one wave per node; 8 lanes x float4; 8 edges/iter.
__global__ __launch_bounds__(256) void k_gather2(const float* __restrict__ hp,
                                                 const int* __restrict__ csr,
                                                 const int* __restrict__ G,
                                                 const float* __restrict__ dinv,
                                                 float* __restrict__ l2,
                                                 int rbase, int first) {
    const int node = (blockIdx.x * 256 + threadIdx.x) >> 6;
    const int lane = threadIdx.x & 63;
    const int l8 = lane & 7;
    const int e8 = lane >> 3;
    const int idx = rbase + node;
    const int off0 = G[idx];
    const int off1 = (idx == NRN - 1) ? E_TOT : G[idx + 1];
    float ax = 0.f, ay = 0.f, az = 0.f, aw = 0.f;
    for (int base = off0; base < off1; base += 64) {
        int m = off1 - base;
        if (m > 64) m = 64;
        const int sv = (lane < m) ? csr[base + lane] : 0;
        const int nq = (m + 7) >> 3;
        for (int q = 0; q < nq; ++q) {
            const int ei = q * 8 + e8;
            const int s = __shfl(sv, ei);
            const float4 v = *(const float4*)(hp + (size_t)s * 32 + l8 * 4);
            const bool ok = ei < m;
            ax += ok ? v.x : 0.f;
            ay += ok ? v.y : 0.f;
            az += ok ? v.z : 0.f;
            aw += ok ? v.w : 0.f;
        }
    }
    ax += __shfl_xor(ax, 8);  ay += __shfl_xor(ay, 8);
    az += __shfl_xor(az, 8);  aw += __shfl_xor(aw, 8);
    ax += __shfl_xor(ax, 16); ay += __shfl_xor(ay, 16);
    az += __shfl_xor(az, 16); aw += __shfl_xor(aw, 16);
    ax += __shfl_xor(ax, 32); ay += __shfl_xor(ay, 32);
    az += __shfl_xor(az, 32); aw += __shfl_xor(aw, 32);
    if (lane < 8) {
        const float dv = dinv[idx];
        float4* dst = (float4*)(l2 + (size_t)node * 32) + l8;
        float4 o;
        if (first) {
            o.x = dv * ax; o.y = dv * ay; o.z = dv * az; o.w = dv * aw;
        } else {
            const float4 pr = *dst;
            o.x = pr.x + dv * ax; o.y = pr.y + dv * ay;
            o.z = pr.z + dv * az; o.w = pr.w + dv * aw;
        }
        *dst = o;
    }
}

// last relation's 32-feat gather fused with VGAE epilogue -> out directly.
__global__ __launch_bounds__(256) void k_gather2_fin(const float* __restrict__ hp,
                                                     const int* __restrict__ csr,
                                                     const int* __restrict__ G,
                                                     const float* __restrict__ dinv,
                                                     const float* __restrict__ l2,
                                                     const float* __restrict__ bmu,
                                                     const float* __restrict__ bls,
                                                     float* __restrict__ outh,
                                                     int rbase) {
    const int node = (blockIdx.x * 256 + threadIdx.x) >> 6;
    const int lane = threadIdx.x & 63;
    const int l8 = lane & 7;
    const int e8 = lane >> 3;
    const int idx = rbase + node;
    const int off0 = G[idx];
    const int off1 = (idx == NRN - 1) ? E_TOT : G[idx + 1];
    float ax = 0.f, ay = 0.f, az = 0.f, aw = 0.f;
    for (int base = off0; base < off1; base += 64) {
        int m = off1 - base;
        if (m > 64) m = 64;
        const int sv = (lane < m) ? csr[base + lane] : 0;
        const int nq = (m + 7) >> 3;
        for (int q = 0; q < nq; ++q) {
            const int ei = q * 8 + e8;
            const int s = __shfl(sv, ei);
            const float4 v = *(const float4*)(hp + (size_t)s * 32 + l8 * 4);
            const bool ok = ei < m;
            ax += ok ? v.x : 0.f;
            ay += ok ? v.y : 0.f;
            az += ok ? v.z : 0.f;
            aw += ok ? v.w : 0.f;
        }
    }
    ax += __shfl_xor(ax, 8);  ay += __shfl_xor(ay, 8);
    az += __shfl_xor(az, 8);  aw += __shfl_xor(aw, 8);
    ax += __shfl_xor(ax, 16); ay += __shfl_xor(ay, 16);
    az += __shfl_xor(az, 16); aw += __shfl_xor(aw, 16);
    ax += __shfl_xor(ax, 32); ay += __shfl_xor(ay, 32);
    az += __shfl_xor(az, 32); aw += __shfl_xor(aw, 32);
    const float dv = dinv[idx];
    float vx = 0.f, vy = 0.f, vz = 0.f, vw = 0.f;
    if (lane < 8) {
        const float4 pr = *((const float4*)(l2 + (size_t)node * 32) + l8);
        vx = pr.x + dv * ax; vy = pr.y + dv * ay;
        vz = pr.z + dv * az; vw = pr.w + dv * aw;
    }
    const float px = __shfl(vx, lane + 4);
    const float py = __shfl(vy, lane + 4);
    const float pz = __shfl(vz, lane + 4);
    const float pw = __shfl(vw, lane + 4);
    if (lane < 4) {
        const int c0 = lane * 4;
        float4 o;
        {
            const float mean = vx + bmu[c0] + bmu[16 + c0] + bmu[32 + c0];
            const float lstd = px + bls[c0] + bls[16 + c0] + bls[32 + c0];
            o.x = mean + jax_noise((unsigned)(node * 16 + c0)) * expf(lstd);
        }
        {
            const float mean = vy + bmu[c0 + 1] + bmu[17 + c0] + bmu[33 + c0];
            const float lstd = py + bls[c0 + 1] + bls[17 + c0] + bls[33 + c0];
            o.y = mean + jax_noise((unsigned)(node * 16 + c0 + 1)) * expf(lstd);
        }
        {
            const float mean = vz + bmu[c0 + 2] + bmu[18 + c0] + bmu[34 + c0];
            const float lstd = pz + bls[c0 + 2] + bls[18 + c0] + bls[34 + c0];
            o.z = mean + jax_noise((unsigned)(node * 16 + c0 + 2)) * expf(lstd);
        }
        {
            const float mean = vw + bmu[c0 + 3] + bmu[19 + c0] + bmu[35 + c0];
            const float lstd = pw + bls[c0 + 3] + bls[19 + c0] + bls[35 + c0];
            o.w = mean + jax_noise((unsigned)(node * 16 + c0 + 3)) * expf(lstd);
        }
        ((float4*)outh)[node * 4 + lane] = o;
    }
}

// ------------------------------------------------------ projections
__global__ __launch_bounds__(256) void k_project1(const float* __restrict__ x,
                                                  const float* __restrict__ W,
                                                  const float* __restrict__ dinv,
                                                  float* __restrict__ out) {
    __shared__ float ws[F_IN * F_HID];
    for (int i = threadIdx.x; i < F_IN * F_HID; i += 256) ws[i] = W[i];
    __syncthreads();
    for (int t = blockIdx.x * 256 + threadIdx.x; t < N_NODES * F_HID;
         t += gridDim.x * 256) {
        const int n = t >> 6;
        const int c = t & 63;
        const float* xr = x + (size_t)n * F_IN;
        float acc = 0.f;
#pragma unroll 16
        for (int k = 0; k < F_IN; ++k) acc = fmaf(xr[k], ws[k * F_HID + c], acc);
        out[t] = acc * dinv[n];
    }
}

__global__ __launch_bounds__(256) void k_project2(const float* __restrict__ h1,
                                                  const float* __restrict__ b0,
                                                  const float* __restrict__ Wmu,
                                                  const float* __restrict__ Wls,
                                                  const float* __restrict__ dinv,
                                                  float* __restrict__ out) {
    __shared__ float ws[F_HID * 32];
    __shared__ float bs[F_HID];
    for (int i = threadIdx.x; i < F_HID * 32; i += 256) {
        const int k = i >> 5, c = i & 31;
        ws[i] = (c < 16) ? Wmu[k * 16 + c] : Wls[k * 16 + (c - 16)];
    }
    if (threadIdx.x < F_HID)
        bs[threadIdx.x] = b0[threadIdx.x] + b0[64 + threadIdx.x] + b0[128 + threadIdx.x];
    __syncthreads();
    for (int t = blockIdx.x * 256 + threadIdx.x; t < N_NODES * 32;
         t += gridDim.x * 256) {
        const int n = t >> 5;
        const int c = t & 31;
        const float* hr = h1 + (size_t)n * F_HID;
        float acc = 0.f;
#pragma unroll 8
        for (int k = 0; k < F_HID; ++k) {
            const float v = fmaxf(hr[k] + bs[k], 0.f);
            acc = fmaf(v, ws[k * 32 + c], acc);
        }
        out[t] = acc * dinv[n];
    }
}

__global__ __launch_bounds__(256) void k_scores(const int* __restrict__ ps,
                                                const int* __restrict__ pd,
                                                const int* __restrict__ ns,
                                                const int* __restrict__ nd,
                                                const float* __restrict__ h,
                                                float* __restrict__ out) {
    const int i = blockIdx.x * 256 + threadIdx.x;
    if (i >= 2 * EP) return;
    const int j = (i < EP) ? i : i - EP;
    const int a = (i < EP) ? ps[j] : ns[j];
    const int b = (i < EP) ? pd[j] : nd[j];
    const float4* ha = (const float4*)(h + (size_t)a * 16);
    const float4* hb = (const float4*)(h + (size_t)b * 16);
    float s = 0.f;
#pragma unroll
    for (int q = 0; q < 4; ++q) {
        const float4 u = ha[q];
        const float4 v = hb[q];
        s += u.x * v.x + u.y * v.y + u.z * v.z + u.w * v.w;
    }
    out[i] = s;
}

// --------------------------------------------- fallback (R7 atomic-scatter)
__global__ __launch_bounds__(256) void k_degrees(const int* __restrict__ es,
                                                 const int* __restrict__ ed,
                                                 float* __restrict__ dout,
                                                 float* __restrict__ din) {
    const int r = blockIdx.y;
    const int e = blockIdx.x * 256 + threadIdx.x;
    const int s = es[r * E_PER + e];
    const int d = ed[r * E_PER + e];
    atomAddF(&dout[r * N_NODES + s], 1.0f);
    atomAddF(&din[r * N_NODES + d], 1.0f);
}

__global__ __launch_bounds__(256) void k_finalize_deg(float* __restrict__ d) {
    const int i = blockIdx.x * 256 + threadIdx.x;
    if (i < 2 * NRN) d[i] = 1.0f / sqrtf(fmaxf(d[i], 1.0f));
}

__global__ __launch_bounds__(256) void k_scatter1(const float* __restrict__ hp,
                                                  const int* __restrict__ es,
                                                  const int* __restrict__ ed,
                                                  const float* __restrict__ din,
                                                  float* __restrict__ acc) {
    const int t = blockIdx.x * 256 + threadIdx.x;
    const int e = t >> 6;
    const int lane = t & 63;
    const int s = es[e];
    const int d = ed[e];
    const float v = hp[s * F_HID + lane] * din[d];
    atomAddF(&acc[d * F_HID + lane], v);
}

__global__ __launch_bounds__(256) void k_scatter2(const float* __restrict__ hp,
                                                  const int* __restrict__ es,
                                                  const int* __restrict__ ed,
                                                  const float* __restrict__ din,
                                                  float* __restrict__ acc) {
    const int t = blockIdx.x * 256 + threadIdx.x;
    const int e = t >> 5;
    const int c = t & 31;
    const int s = es[e];
    const int d = ed[e];
    const float v = hp[s * 32 + c] * din[d];
    atomAddF(&acc[d * 32 + c], v);
}

__global__ __launch_bounds__(256) void k_finalize(const float* __restrict__ l2,
                                                  const float* __restrict__ bmu,
                                                  const float* __restrict__ bls,
                                                  float* __restrict__ outh) {
    const int i = blockIdx.x * 256 + threadIdx.x;
    const int n = i >> 4, c = i & 15;
    const float mean = l2[n * 32 + c] + bmu[c] + bmu[16 + c] + bmu[32 + c];
    const float lstd = l2[n * 32 + 16 + c] + bls[c] + bls[16 + c] + bls[32 + c];
    const float z = jax_noise((unsigned)i);
    outh[i] = mean + z * expf(lstd);
}

extern "C" void kernel_launch(void* const* d_in, const int* in_sizes, int n_in,
                              void* d_out, int out_size, void* d_ws, size_t ws_size,
                              hipStream_t stream) {
    const float* x   = (const float*)d_in[0];
    const float* W0  = (const float*)d_in[1];
    const float* b0  = (const float*)d_in[2];
    const float* Wmu = (const float*)d_in[3];
    const float* bmu = (const float*)d_in[4];
    const float* Wls = (const float*)d_in[5];
    const float* bls = (const float*)d_in[6];
    const int* es = (const int*)d_in[7];
    const int* ed = (const int*)d_in[8];
    const int* ps = (const int*)d_in[9];
    const int* pd = (const int*)d_in[10];
    const int* ns = (const int*)d_in[11];
    const int* nd = (const int*)d_in[12];
    float* out = (float*)d_out;
    float* wsf = (float*)d_ws;

    if (ws_size >= (size_t)WS_NEED_CSR * sizeof(float)) {
        // ---------------- CSR path ----------------
        int*   doutc   = (int*)(wsf + OFF_DOUT);    // int counts -> float rsqrt
        float* doutf   = wsf + OFF_DOUT;            // float view after scanC
        float* dinv_in = wsf + OFF_DINVIN;
        int*   cnt     = (int*)(wsf + OFF_CNT);
        int*   G       = (int*)(wsf + OFF_G);
        int*   bsum    = (int*)(wsf + OFF_BSUM);
        int*   csr     = (int*)(wsf + OFF_CSR);
        int*   eslot   = (int*)(wsf + OFF_ESLOT);   // aliases hproj
        float* hproj   = wsf + OFF_HPROJ;
        float* h1acc   = wsf + OFF_H1;
        float* l2acc   = wsf + OFF_L2;

        hipMemsetAsync(doutc, 0, (size_t)NRN * sizeof(int), stream);
        hipMemsetAsync(cnt, 0, (size_t)NRN * sizeof(int), stream);

        k_histin<<<dim3(NBLK, NSEG, NREL), 256, 0, stream>>>(ed, cnt, eslot);
        k_histout<<<dim3(NBLK, NSEG, NREL), 256, 0, stream>>>(es, doutc);
        k_scanA<<<294, 256, 0, stream>>>(cnt, bsum);
        k_scanB<<<1, 512, 0, stream>>>(bsum);
        k_scanC<<<294, 256, 0, stream>>>(cnt, bsum, G, dinv_in, doutc);
        k_fill<<<dim3(E_PER / 256, NREL), 256, 0, stream>>>(es, ed, eslot, G, csr);

        for (int r = 0; r < NREL; ++r) {
            k_project1<<<1024, 256, 0, stream>>>(
                x, W0 + (size_t)r * F_IN * F_HID, doutf + (size_t)r * N_NODES, hproj);
            k_gather1<<<N_NODES / 4, 256, 0, stream>>>(
                hproj, csr, G, dinv_in, h1acc, r * N_NODES, r == 0);
        }
        for (int r = 0; r < NREL; ++r) {
            k_project2<<<512, 256, 0, stream>>>(
                h1acc, b0, Wmu + (size_t)r * F_HID * F_OUT,
                Wls + (size_t)r * F_HID * F_OUT, doutf + (size_t)r * N_NODES, hproj);
            if (r < NREL - 1) {
                k_gather2<<<N_NODES / 4, 256, 0, stream>>>(
                    hproj, csr, G, dinv_in, l2acc, r * N_NODES, r == 0);
            } else {
                k_gather2_fin<<<N_NODES / 4, 256, 0, stream>>>(
                    hproj, csr, G, dinv_in, l2acc, bmu, bls, out + 2 * EP,
                    r * N_NODES);
            }
        }
        k_scores<<<(2 * EP + 255) / 256, 256, 0, stream>>>(
            ps, pd, ns, nd, out + 2 * EP, out);
    } else {
        // ---------------- fallback: proven R7 atomic path ----------------
        float* dinv_out = wsf + ODINV_OUT;
        float* dinv_in  = wsf + ODINV_IN;
        float* h1acc    = wsf + OH1ACC;
        float* hproj    = wsf + OHPROJ;
        float* l2acc    = wsf + OL2ACC;

        hipMemsetAsync(dinv_out, 0, (size_t)2 * NRN * sizeof(float), stream);
        hipMemsetAsync(h1acc, 0, (size_t)N_NODES * F_HID * sizeof(float), stream);
        hipMemsetAsync(l2acc, 0, (size_t)N_NODES * 32 * sizeof(float), stream);

        k_degrees<<<dim3(E_PER / 256, NREL), 256, 0, stream>>>(es, ed, dinv_out, dinv_in);
        k_finalize_deg<<<(2 * NRN + 255) / 256, 256, 0, stream>>>(wsf);

        for (int r = 0; r < NREL; ++r) {
            k_project1<<<1024, 256, 0, stream>>>(
                x, W0 + (size_t)r * F_IN * F_HID, dinv_out + (size_t)r * N_NODES, hproj);
            k_scatter1<<<E_PER / 4, 256, 0, stream>>>(
                hproj, es + (size_t)r * E_PER, ed + (size_t)r * E_PER,
                dinv_in + (size_t)r * N_NODES, h1acc);
        }
        for (int r = 0; r < NREL; ++r) {
            k_project2<<<512, 256, 0, stream>>>(
                h1acc, b0, Wmu + (size_t)r * F_HID * F_OUT,
                Wls + (size_t)r * F_HID * F_OUT, dinv_out + (size_t)r * N_NODES, hproj);
            k_scatter2<<<E_PER / 8, 256, 0, stream>>>(
                hproj, es + (size_t)r * E_PER, ed + (size_t)r * E_PER,
                dinv_in + (size_t)r * N_NODES, l2acc);
        }
        k_finalize<<<N_NODES * F_OUT / 256, 256, 0, stream>>>(
            l2acc, bmu, bls, out + 2 * EP);
        k_scores<<<(2 * EP + 255) / 256, 256, 0, stream>>>(
            ps, pd, ns, nd, out + 2 * EP, out);
    }
}

// Round 12
// 1235.494 us; speedup vs baseline: 2.1781x; 1.2616x over previous
//
#include <hip/hip_runtime.h>
#include <math.h>

#define N_NODES 100000
#define NREL 3
#define E_PER 1600000
#define E_TOT 4800000
#define EP 500000
#define F_IN 128
#define F_HID 64
#define F_OUT 16
#define NRN 300000   // NREL*N_NODES

// two-level histogram params
#define NSEG 7
#define SEGSZ 16000          // 62.5 KB static LDS, 2 blocks/CU
#define NBLK 32
#define CHUNK (E_PER / NBLK) // 50000 edges/block (div by 4)

// ---------------- CSR-path ws layout (element offsets) ----------------
#define OFF_DOUT    0           // 300000: int counts -> float rsqrt in place
#define OFF_DINVIN  300000      // 300000 f
#define OFF_CNT     600000      // 300000 i: in-deg counts
#define OFF_G       900000      // 300000 i: CSR offsets (exclusive prefix)
#define OFF_BSUM    1200000     // 1024 i
#define OFF_CSR     1201024     // 4800000 i: dst-sorted src indices
#define OFF_ESLOT   6001024     // 4800000 i  (alias w/ hproj)
#define OFF_HPROJ   6001024     // 6400000 f
#define OFF_H1      12401024    // 6400000 f
#define OFF_L2      18801024    // 3200000 f
#define WS_NEED_CSR 22001024    // 88.0 MB — proven to fit (R8-R11)
// ---------------- fallback (R7 atomic-scatter) layout ----------------
#define ODINV_OUT 0
#define ODINV_IN  300000
#define OH1ACC    600000
#define OHPROJ    7000000
#define OL2ACC    13400000

__device__ __forceinline__ float atomAddF(float* p, float v) {
    return unsafeAtomicAdd(p, v);
}

__device__ __forceinline__ unsigned rotl32(unsigned x, unsigned d) {
    return (x << d) | (x >> (32u - d));
}

// jax.random.normal(key(42), (100000,16)) — partitionable threefry2x32,
// counter (0,i), key (0,42), XOR-folded output words. Verified PASS R7-R11.
__device__ float jax_noise(unsigned i) {
    const unsigned ks0 = 0u, ks1 = 42u;
    const unsigned ks2 = ks0 ^ ks1 ^ 0x1BD11BDAu;
    unsigned x0 = 0u + ks0;
    unsigned x1 = i + ks1;
#define TFR(r) { x0 += x1; x1 = rotl32(x1, r); x1 ^= x0; }
    TFR(13) TFR(15) TFR(26) TFR(6)
    x0 += ks1; x1 += ks2 + 1u;
    TFR(17) TFR(29) TFR(16) TFR(24)
    x0 += ks2; x1 += ks0 + 2u;
    TFR(13) TFR(15) TFR(26) TFR(6)
    x0 += ks0; x1 += ks1 + 3u;
    TFR(17) TFR(29) TFR(16) TFR(24)
    x0 += ks1; x1 += ks2 + 4u;
    TFR(13) TFR(15) TFR(26) TFR(6)
    x0 += ks2; x1 += ks0 + 5u;
#undef TFR
    const unsigned bits = x0 ^ x1;
    float f = __uint_as_float((bits >> 9) | 0x3f800000u) - 1.0f;
    const float lo = -0.99999994f;
    float u = fmaxf(lo, f * 2.0f + lo);
    float w = -log1pf(-u * u);
    float p;
    if (w < 5.0f) {
        w -= 2.5f;
        p = 2.81022636e-08f;
        p = fmaf(p, w, 3.43273939e-07f);
        p = fmaf(p, w, -3.5233877e-06f);
        p = fmaf(p, w, -4.39150654e-06f);
        p = fmaf(p, w, 0.00021858087f);
        p = fmaf(p, w, -0.00125372503f);
        p = fmaf(p, w, -0.00417768164f);
        p = fmaf(p, w, 0.246640727f);
        p = fmaf(p, w, 1.50140941f);
    } else {
        w = sqrtf(w) - 3.0f;
        p = -0.000200214257f;
        p = fmaf(p, w, 0.000100950558f);
        p = fmaf(p, w, 0.00134934322f);
        p = fmaf(p, w, -0.00367342844f);
        p = fmaf(p, w, 0.00573950773f);
        p = fmaf(p, w, -0.0076224613f);
        p = fmaf(p, w, 0.00943887047f);
        p = fmaf(p, w, 1.00167406f);
        p = fmaf(p, w, 2.83297682f);
    }
    return 1.41421356237f * (p * u);
}

// ------------------------------------------------------ two-level histograms
// in-degree counts + per-edge CSR slot. 512 threads, int4 loads (4-edge ILP).
// grid (NBLK, NSEG, NREL) x 512; 62.5 KB LDS -> 2 blocks/CU, 16 waves/CU.
__global__ __launch_bounds__(512) void k_histin(const int* __restrict__ ed,
                                                int* __restrict__ cnt,
                                                int* __restrict__ eslot) {
    __shared__ int lds[SEGSZ];
    const int r = blockIdx.z, g = blockIdx.y, b = blockIdx.x;
    const int lo = g * SEGSZ;
    const int hi = min(lo + SEGSZ, N_NODES);
    const int nbins = hi - lo;
    for (int i = threadIdx.x; i < nbins; i += 512) lds[i] = 0;
    __syncthreads();
    const int e0 = r * E_PER + b * CHUNK;
    const int e1 = e0 + CHUNK;
    // phase 1: private count, 4 edges/thread/iter
    for (int e = e0 + threadIdx.x * 4; e + 4 <= e1; e += 512 * 4) {
        const int4 d4 = *(const int4*)(ed + e);
        if (d4.x >= lo && d4.x < hi) atomicAdd(&lds[d4.x - lo], 1);
        if (d4.y >= lo && d4.y < hi) atomicAdd(&lds[d4.y - lo], 1);
        if (d4.z >= lo && d4.z < hi) atomicAdd(&lds[d4.z - lo], 1);
        if (d4.w >= lo && d4.w < hi) atomicAdd(&lds[d4.w - lo], 1);
    }
    __syncthreads();
    // phase 2: flush; fetch-add return = this block's exclusive base per bin
    for (int i = threadIdx.x; i < nbins; i += 512) {
        const int c = lds[i];
        lds[i] = c ? atomicAdd(&cnt[r * N_NODES + lo + i], c) : 0;
    }
    __syncthreads();
    // phase 3: final slot = LDS fetch-add from base
    for (int e = e0 + threadIdx.x * 4; e + 4 <= e1; e += 512 * 4) {
        const int4 d4 = *(const int4*)(ed + e);
        if (d4.x >= lo && d4.x < hi) eslot[e]     = atomicAdd(&lds[d4.x - lo], 1);
        if (d4.y >= lo && d4.y < hi) eslot[e + 1] = atomicAdd(&lds[d4.y - lo], 1);
        if (d4.z >= lo && d4.z < hi) eslot[e + 2] = atomicAdd(&lds[d4.z - lo], 1);
        if (d4.w >= lo && d4.w < hi) eslot[e + 3] = atomicAdd(&lds[d4.w - lo], 1);
    }
}

// out-degree int counts, LDS-privatized (no slots). Same TLP/ILP treatment.
__global__ __launch_bounds__(512) void k_histout(const int* __restrict__ es,
                                                 int* __restrict__ dout) {
    __shared__ int lds[SEGSZ];
    const int r = blockIdx.z, g = blockIdx.y, b = blockIdx.x;
    const int lo = g * SEGSZ;
    const int hi = min(lo + SEGSZ, N_NODES);
    const int nbins = hi - lo;
    for (int i = threadIdx.x; i < nbins; i += 512) lds[i] = 0;
    __syncthreads();
    const int e0 = r * E_PER + b * CHUNK;
    const int e1 = e0 + CHUNK;
    for (int e = e0 + threadIdx.x * 4; e + 4 <= e1; e += 512 * 4) {
        const int4 s4 = *(const int4*)(es + e);
        if (s4.x >= lo && s4.x < hi) atomicAdd(&lds[s4.x - lo], 1);
        if (s4.y >= lo && s4.y < hi) atomicAdd(&lds[s4.y - lo], 1);
        if (s4.z >= lo && s4.z < hi) atomicAdd(&lds[s4.z - lo], 1);
        if (s4.w >= lo && s4.w < hi) atomicAdd(&lds[s4.w - lo], 1);
    }
    __syncthreads();
    for (int i = threadIdx.x; i < nbins; i += 512) {
        const int c = lds[i];
        if (c) atomicAdd(&dout[r * N_NODES + lo + i], c);
    }
}

__global__ __launch_bounds__(256) void k_scanA(const int* __restrict__ cnt,
                                               int* __restrict__ bsum) {
    __shared__ int red[256];
    const int base = blockIdx.x * 1024 + threadIdx.x * 4;
    int s = 0;
#pragma unroll
    for (int q = 0; q < 4; ++q) {
        const int i = base + q;
        s += (i < NRN) ? cnt[i] : 0;
    }
    red[threadIdx.x] = s;
    __syncthreads();
    for (int w = 128; w > 0; w >>= 1) {
        if (threadIdx.x < w) red[threadIdx.x] += red[threadIdx.x + w];
        __syncthreads();
    }
    if (threadIdx.x == 0) bsum[blockIdx.x] = red[0];
}

__global__ __launch_bounds__(512) void k_scanB(int* __restrict__ bsum) {
    __shared__ int sc[512];
    const int t = threadIdx.x;
    sc[t] = (t < 294) ? bsum[t] : 0;
    __syncthreads();
    for (int o = 1; o < 512; o <<= 1) {
        const int v = (t >= o) ? sc[t - o] : 0;
        __syncthreads();
        sc[t] += v;
        __syncthreads();
    }
    bsum[t] = (t > 0) ? sc[t - 1] : 0;
}

__global__ __launch_bounds__(256) void k_scanC(const int* __restrict__ cnt,
                                               const int* __restrict__ bsum,
                                               int* __restrict__ G,
                                               float* __restrict__ dinv_in,
                                               int* doutc) {
    __shared__ int sc[256];
    const int t = threadIdx.x;
    const int base = blockIdx.x * 1024 + t * 4;
    int v[4];
    int ts = 0;
#pragma unroll
    for (int q = 0; q < 4; ++q) {
        const int i = base + q;
        v[q] = (i < NRN) ? cnt[i] : 0;
        ts += v[q];
    }
    sc[t] = ts;
    __syncthreads();
    for (int o = 1; o < 256; o <<= 1) {
        const int x = (t >= o) ? sc[t - o] : 0;
        __syncthreads();
        sc[t] += x;
        __syncthreads();
    }
    int run = bsum[blockIdx.x] + ((t > 0) ? sc[t - 1] : 0);
#pragma unroll
    for (int q = 0; q < 4; ++q) {
        const int i = base + q;
        if (i < NRN) {
            G[i] = run;
            dinv_in[i] = rsqrtf((float)max(v[q], 1));
            const int oc = doutc[i];
            ((float*)doutc)[i] = rsqrtf((float)max(oc, 1));
        }
        run += v[q];
    }
}

// atomic-free CSR fill, 4 edges/thread via int4.
__global__ __launch_bounds__(256) void k_fill(const int* __restrict__ es,
                                              const int* __restrict__ ed,
                                              const int* __restrict__ eslot,
                                              const int* __restrict__ G,
                                              int* __restrict__ csr) {
    const int r = blockIdx.y;
    const int e = (blockIdx.x * 256 + threadIdx.x) * 4;
    if (e + 4 > E_PER) return;
    const int gid = r * E_PER + e;
    const int4 s4 = *(const int4*)(es + gid);
    const int4 d4 = *(const int4*)(ed + gid);
    const int4 l4 = *(const int4*)(eslot + gid);
    const int rb = r * N_NODES;
    csr[G[rb + d4.x] + l4.x] = s4.x;
    csr[G[rb + d4.y] + l4.y] = s4.y;
    csr[G[rb + d4.z] + l4.z] = s4.z;
    csr[G[rb + d4.w] + l4.w] = s4.w;
}

// gather 64 feats: one wave per dst node; 16 lanes x float4; 4 edges/iter.
__global__ __launch_bounds__(256) void k_gather1(const float* __restrict__ hp,
                                                 const int* __restrict__ csr,
                                                 const int* __restrict__ G,
                                                 const float* __restrict__ dinv,
                                                 float* __restrict__ h1,
                                                 int rbase, int first) {
    const int node = (blockIdx.x * 256 + threadIdx.x) >> 6;
    const int lane = threadIdx.x & 63;
    const int l16 = lane & 15;
    const int e4 = lane >> 4;
    const int idx = rbase + node;
    const int off0 = G[idx];
    const int off1 = (idx == NRN - 1) ? E_TOT : G[idx + 1];
    float ax = 0.f, ay = 0.f, az = 0.f, aw = 0.f;
    for (int base = off0; base < off1; base += 64) {
        int m = off1 - base;
        if (m > 64) m = 64;
        const int sv = (lane < m) ? csr[base + lane] : 0;
        const int nq = (m + 3) >> 2;
        for (int q = 0; q < nq; ++q) {
            const int ei = q * 4 + e4;
            const int s = __shfl(sv, ei);
            const float4 v = *(const float4*)(hp + (size_t)s * F_HID + l16 * 4);
            const bool ok = ei < m;
            ax += ok ? v.x : 0.f;
            ay += ok ? v.y : 0.f;
            az += ok ? v.z : 0.f;
            aw += ok ? v.w : 0.f;
        }
    }
    ax += __shfl_xor(ax, 16); ay += __shfl_xor(ay, 16);
    az += __shfl_xor(az, 16); aw += __shfl_xor(aw, 16);
    ax += __shfl_xor(ax, 32); ay += __shfl_xor(ay, 32);
    az += __shfl_xor(az, 32); aw += __shfl_xor(aw, 32);
    if (lane < 16) {
        const float dv = dinv[idx];
        float4* dst = (float4*)(h1 + (size_t)node * F_HID) + l16;
        float4 o;
        if (first) {
            o.x = dv * ax; o.y = dv * ay; o.z = dv * az; o.w = dv * aw;
        } else {
            const float4 pr = *dst;
            o.x = pr.x + dv * ax; o.y = pr.y + dv * ay;
            o.z = pr.z + dv * az; o.w = pr.w + dv * aw;
        }
        *dst = o;
    }
}

// gather 32 feats (mu||ls): one wave per node; 8 lanes x float4; 8 edges/iter.
__global__ __launch_bounds__(256) void k_gather2(const float* __restrict__ hp,
                                                 const int* __restrict__ csr,
                                                 const int* __restrict__ G,
                                                 const float* __restrict__ dinv,
                                                 float* __restrict__ l2,
                                                 int rbase, int first) {
    const int node = (blockIdx.x * 256 + threadIdx.x) >> 6;
    const int lane = threadIdx.x & 63;
    const int l8 = lane & 7;
    const int e8 = lane >> 3;
    const int idx = rbase + node;
    const int off0 = G[idx];
    const int off1 = (idx == NRN - 1) ? E_TOT : G[idx + 1];
    float ax = 0.f, ay = 0.f, az = 0.f, aw = 0.f;
    for (int base = off0; base < off1; base += 64) {
        int m = off1 - base;
        if (m > 64) m = 64;
        const int sv = (lane < m) ? csr[base + lane] : 0;
        const int nq = (m + 7) >> 3;
        for (int q = 0; q < nq; ++q) {
            const int ei = q * 8 + e8;
            const int s = __shfl(sv, ei);
            const float4 v = *(const float4*)(hp + (size_t)s * 32 + l8 * 4);
            const bool ok = ei < m;
            ax += ok ? v.x : 0.f;
            ay += ok ? v.y : 0.f;
            az += ok ? v.z : 0.f;
            aw += ok ? v.w : 0.f;
        }
    }
    ax += __shfl_xor(ax, 8);  ay += __shfl_xor(ay, 8);
    az += __shfl_xor(az, 8);  aw += __shfl_xor(aw, 8);
    ax += __shfl_xor(ax, 16); ay += __shfl_xor(ay, 16);
    az += __shfl_xor(az, 16); aw += __shfl_xor(aw, 16);
    ax += __shfl_xor(ax, 32); ay += __shfl_xor(ay, 32);
    az += __shfl_xor(az, 32); aw += __shfl_xor(aw, 32);
    if (lane < 8) {
        const float dv = dinv[idx];
        float4* dst = (float4*)(l2 + (size_t)node * 32) + l8;
        float4 o;
        if (first) {
            o.x = dv * ax; o.y = dv * ay; o.z = dv * az; o.w = dv * aw;
        } else {
            const float4 pr = *dst;
            o.x = pr.x + dv * ax; o.y = pr.y + dv * ay;
            o.z = pr.z + dv * az; o.w = pr.w + dv * aw;
        }
        *dst = o;
    }
}

// last relation's 32-feat gather fused with VGAE epilogue -> out directly.
__global__ __launch_bounds__(256) void k_gather2_fin(const float* __restrict__ hp,
                                                     const int* __restrict__ csr,
                                                     const int* __restrict__ G,
                                                     const float* __restrict__ dinv,
                                                     const float* __restrict__ l2,
                                                     const float* __restrict__ bmu,
                                                     const float* __restrict__ bls,
                                                     float* __restrict__ outh,
                                                     int rbase) {
    const int node = (blockIdx.x * 256 + threadIdx.x) >> 6;
    const int lane = threadIdx.x & 63;
    const int l8 = lane & 7;
    const int e8 = lane >> 3;
    const int idx = rbase + node;
    const int off0 = G[idx];
    const int off1 = (idx == NRN - 1) ? E_TOT : G[idx + 1];
    float ax = 0.f, ay = 0.f, az = 0.f, aw = 0.f;
    for (int base = off0; base < off1; base += 64) {
        int m = off1 - base;
        if (m > 64) m = 64;
        const int sv = (lane < m) ? csr[base + lane] : 0;
        const int nq = (m + 7) >> 3;
        for (int q = 0; q < nq; ++q) {
            const int ei = q * 8 + e8;
            const int s = __shfl(sv, ei);
            const float4 v = *(const float4*)(hp + (size_t)s * 32 + l8 * 4);
            const bool ok = ei < m;
            ax += ok ? v.x : 0.f;
            ay += ok ? v.y : 0.f;
            az += ok ? v.z : 0.f;
            aw += ok ? v.w : 0.f;
        }
    }
    ax += __shfl_xor(ax, 8);  ay += __shfl_xor(ay, 8);
    az += __shfl_xor(az, 8);  aw += __shfl_xor(aw, 8);
    ax += __shfl_xor(ax, 16); ay += __shfl_xor(ay, 16);
    az += __shfl_xor(az, 16); aw += __shfl_xor(aw, 16);
    ax += __shfl_xor(ax, 32); ay += __shfl_xor(ay, 32);
    az += __shfl_xor(az, 32); aw += __shfl_xor(aw, 32);
    const float dv = dinv[idx];
    float vx = 0.f, vy = 0.f, vz = 0.f, vw = 0.f;
    if (lane < 8) {
        const float4 pr = *((const float4*)(l2 + (size_t)node * 32) + l8);
        vx = pr.x + dv * ax; vy = pr.y + dv * ay;
        vz = pr.z + dv * az; vw = pr.w + dv * aw;
    }
    const float px = __shfl(vx, lane + 4);
    const float py = __shfl(vy, lane + 4);
    const float pz = __shfl(vz, lane + 4);
    const float pw = __shfl(vw, lane + 4);
    if (lane < 4) {
        const int c0 = lane * 4;
        float4 o;
        {
            const float mean = vx + bmu[c0] + bmu[16 + c0] + bmu[32 + c0];
            const float lstd = px + bls[c0] + bls[16 + c0] + bls[32 + c0];
            o.x = mean + jax_noise((unsigned)(node * 16 + c0)) * expf(lstd);
        }
        {
            const float mean = vy + bmu[c0 + 1] + bmu[17 + c0] + bmu[33 + c0];
            const float lstd = py + bls[c0 + 1] + bls[17 + c0] + bls[33 + c0];
            o.y = mean + jax_noise((unsigned)(node * 16 + c0 + 1)) * expf(lstd);
        }
        {
            const float mean = vz + bmu[c0 + 2] + bmu[18 + c0] + bmu[34 + c0];
            const float lstd = pz + bls[c0 + 2] + bls[18 + c0] + bls[34 + c0];
            o.z = mean + jax_noise((unsigned)(node * 16 + c0 + 2)) * expf(lstd);
        }
        {
            const float mean = vw + bmu[c0 + 3] + bmu[19 + c0] + bmu[35 + c0];
            const float lstd = pw + bls[c0 + 3] + bls[19 + c0] + bls[35 + c0];
            o.w = mean + jax_noise((unsigned)(node * 16 + c0 + 3)) * expf(lstd);
        }
        ((float4*)outh)[node * 4 + lane] = o;
    }
}

// ------------------------------------------------------ projections
__global__ __launch_bounds__(256) void k_project1(const float* __restrict__ x,
                                                  const float* __restrict__ W,
                                                  const float* __restrict__ dinv,
                                                  float* __restrict__ out) {
    __shared__ float ws[F_IN * F_HID];
    for (int i = threadIdx.x; i < F_IN * F_HID; i += 256) ws[i] = W[i];
    __syncthreads();
    for (int t = blockIdx.x * 256 + threadIdx.x; t < N_NODES * F_HID;
         t += gridDim.x * 256) {
        const int n = t >> 6;
        const int c = t & 63;
        const float* xr = x + (size_t)n * F_IN;
        float acc = 0.f;
#pragma unroll 16
        for (int k = 0; k < F_IN; ++k) acc = fmaf(xr[k], ws[k * F_HID + c], acc);
        out[t] = acc * dinv[n];
    }
}

__global__ __launch_bounds__(256) void k_project2(const float* __restrict__ h1,
                                                  const float* __restrict__ b0,
                                                  const float* __restrict__ Wmu,
                                                  const float* __restrict__ Wls,
                                                  const float* __restrict__ dinv,
                                                  float* __restrict__ out) {
    __shared__ float ws[F_HID * 32];
    __shared__ float bs[F_HID];
    for (int i = threadIdx.x; i < F_HID * 32; i += 256) {
        const int k = i >> 5, c = i & 31;
        ws[i] = (c < 16) ? Wmu[k * 16 + c] : Wls[k * 16 + (c - 16)];
    }
    if (threadIdx.x < F_HID)
        bs[threadIdx.x] = b0[threadIdx.x] + b0[64 + threadIdx.x] + b0[128 + threadIdx.x];
    __syncthreads();
    for (int t = blockIdx.x * 256 + threadIdx.x; t < N_NODES * 32;
         t += gridDim.x * 256) {
        const int n = t >> 5;
        const int c = t & 31;
        const float* hr = h1 + (size_t)n * F_HID;
        float acc = 0.f;
#pragma unroll 8
        for (int k = 0; k < F_HID; ++k) {
            const float v = fmaxf(hr[k] + bs[k], 0.f);
            acc = fmaf(v, ws[k * 32 + c], acc);
        }
        out[t] = acc * dinv[n];
    }
}

__global__ __launch_bounds__(256) void k_scores(const int* __restrict__ ps,
                                                const int* __restrict__ pd,
                                                const int* __restrict__ ns,
                                                const int* __restrict__ nd,
                                                const float* __restrict__ h,
                                                float* __restrict__ out) {
    const int i = blockIdx.x * 256 + threadIdx.x;
    if (i >= 2 * EP) return;
    const int j = (i < EP) ? i : i - EP;
    const int a = (i < EP) ? ps[j] : ns[j];
    const int b = (i < EP) ? pd[j] : nd[j];
    const float4* ha = (const float4*)(h + (size_t)a * 16);
    const float4* hb = (const float4*)(h + (size_t)b * 16);
    float s = 0.f;
#pragma unroll
    for (int q = 0; q < 4; ++q) {
        const float4 u = ha[q];
        const float4 v = hb[q];
        s += u.x * v.x + u.y * v.y + u.z * v.z + u.w * v.w;
    }
    out[i] = s;
}

// --------------------------------------------- fallback (R7 atomic-scatter)
__global__ __launch_bounds__(256) void k_degrees(const int* __restrict__ es,
                                                 const int* __restrict__ ed,
                                                 float* __restrict__ dout,
                                                 float* __restrict__ din) {
    const int r = blockIdx.y;
    const int e = blockIdx.x * 256 + threadIdx.x;
    const int s = es[r * E_PER + e];
    const int d = ed[r * E_PER + e];
    atomAddF(&dout[r * N_NODES + s], 1.0f);
    atomAddF(&din[r * N_NODES + d], 1.0f);
}

__global__ __launch_bounds__(256) void k_finalize_deg(float* __restrict__ d) {
    const int i = blockIdx.x * 256 + threadIdx.x;
    if (i < 2 * NRN) d[i] = 1.0f / sqrtf(fmaxf(d[i], 1.0f));
}

__global__ __launch_bounds__(256) void k_scatter1(const float* __restrict__ hp,
                                                  const int* __restrict__ es,
                                                  const int* __restrict__ ed,
                                                  const float* __restrict__ din,
                                                  float* __restrict__ acc) {
    const int t = blockIdx.x * 256 + threadIdx.x;
    const int e = t >> 6;
    const int lane = t & 63;
    const int s = es[e];
    const int d = ed[e];
    const float v = hp[s * F_HID + lane] * din[d];
    atomAddF(&acc[d * F_HID + lane], v);
}

__global__ __launch_bounds__(256) void k_scatter2(const float* __restrict__ hp,
                                                  const int* __restrict__ es,
                                                  const int* __restrict__ ed,
                                                  const float* __restrict__ din,
                                                  float* __restrict__ acc) {
    const int t = blockIdx.x * 256 + threadIdx.x;
    const int e = t >> 5;
    const int c = t & 31;
    const int s = es[e];
    const int d = ed[e];
    const float v = hp[s * 32 + c] * din[d];
    atomAddF(&acc[d * 32 + c], v);
}

__global__ __launch_bounds__(256) void k_finalize(const float* __restrict__ l2,
                                                  const float* __restrict__ bmu,
                                                  const float* __restrict__ bls,
                                                  float* __restrict__ outh) {
    const int i = blockIdx.x * 256 + threadIdx.x;
    const int n = i >> 4, c = i & 15;
    const float mean = l2[n * 32 + c] + bmu[c] + bmu[16 + c] + bmu[32 + c];
    const float lstd = l2[n * 32 + 16 + c] + bls[c] + bls[16 + c] + bls[32 + c];
    const float z = jax_noise((unsigned)i);
    outh[i] = mean + z * expf(lstd);
}

extern "C" void kernel_launch(void* const* d_in, const int* in_sizes, int n_in,
                              void* d_out, int out_size, void* d_ws, size_t ws_size,
                              hipStream_t stream) {
    const float* x   = (const float*)d_in[0];
    const float* W0  = (const float*)d_in[1];
    const float* b0  = (const float*)d_in[2];
    const float* Wmu = (const float*)d_in[3];
    const float* bmu = (const float*)d_in[4];
    const float* Wls = (const float*)d_in[5];
    const float* bls = (const float*)d_in[6];
    const int* es = (const int*)d_in[7];
    const int* ed = (const int*)d_in[8];
    const int* ps = (const int*)d_in[9];
    const int* pd = (const int*)d_in[10];
    const int* ns = (const int*)d_in[11];
    const int* nd = (const int*)d_in[12];
    float* out = (float*)d_out;
    float* wsf = (float*)d_ws;

    if (ws_size >= (size_t)WS_NEED_CSR * sizeof(float)) {
        // ---------------- CSR path ----------------
        int*   doutc   = (int*)(wsf + OFF_DOUT);    // int counts -> float rsqrt
        float* doutf   = wsf + OFF_DOUT;            // float view after scanC
        float* dinv_in = wsf + OFF_DINVIN;
        int*   cnt     = (int*)(wsf + OFF_CNT);
        int*   G       = (int*)(wsf + OFF_G);
        int*   bsum    = (int*)(wsf + OFF_BSUM);
        int*   csr     = (int*)(wsf + OFF_CSR);
        int*   eslot   = (int*)(wsf + OFF_ESLOT);   // aliases hproj
        float* hproj   = wsf + OFF_HPROJ;
        float* h1acc   = wsf + OFF_H1;
        float* l2acc   = wsf + OFF_L2;

        hipMemsetAsync(doutc, 0, (size_t)NRN * sizeof(int), stream);
        hipMemsetAsync(cnt, 0, (size_t)NRN * sizeof(int), stream);

        k_histin<<<dim3(NBLK, NSEG, NREL), 512, 0, stream>>>(ed, cnt, eslot);
        k_histout<<<dim3(NBLK, NSEG, NREL), 512, 0, stream>>>(es, doutc);
        k_scanA<<<294, 256, 0, stream>>>(cnt, bsum);
        k_scanB<<<1, 512, 0, stream>>>(bsum);
        k_scanC<<<294, 256, 0, stream>>>(cnt, bsum, G, dinv_in, doutc);
        k_fill<<<dim3((E_PER / 4 + 255) / 256, NREL), 256, 0, stream>>>(
            es, ed, eslot, G, csr);

        for (int r = 0; r < NREL; ++r) {
            k_project1<<<1024, 256, 0, stream>>>(
                x, W0 + (size_t)r * F_IN * F_HID, doutf + (size_t)r * N_NODES, hproj);
            k_gather1<<<N_NODES / 4, 256, 0, stream>>>(
                hproj, csr, G, dinv_in, h1acc, r * N_NODES, r == 0);
        }
        for (int r = 0; r < NREL; ++r) {
            k_project2<<<512, 256, 0, stream>>>(
                h1acc, b0, Wmu + (size_t)r * F_HID * F_OUT,
                Wls + (size_t)r * F_HID * F_OUT, doutf + (size_t)r * N_NODES, hproj);
            if (r < NREL - 1) {
                k_gather2<<<N_NODES / 4, 256, 0, stream>>>(
                    hproj, csr, G, dinv_in, l2acc, r * N_NODES, r == 0);
            } else {
                k_gather2_fin<<<N_NODES / 4, 256, 0, stream>>>(
                    hproj, csr, G, dinv_in, l2acc, bmu, bls, out + 2 * EP,
                    r * N_NODES);
            }
        }
        k_scores<<<(2 * EP + 255) / 256, 256, 0, stream>>>(
            ps, pd, ns, nd, out + 2 * EP, out);
    } else {
        // ---------------- fallback: proven R7 atomic path ----------------
        float* dinv_out = wsf + ODINV_OUT;
        float* dinv_in  = wsf + ODINV_IN;
        float* h1acc    = wsf + OH1ACC;
        float* hproj    = wsf + OHPROJ;
        float* l2acc    = wsf + OL2ACC;

        hipMemsetAsync(dinv_out, 0, (size_t)2 * NRN * sizeof(float), stream);
        hipMemsetAsync(h1acc, 0, (size_t)N_NODES * F_HID * sizeof(float), stream);
        hipMemsetAsync(l2acc, 0, (size_t)N_NODES * 32 * sizeof(float), stream);

        k_degrees<<<dim3(E_PER / 256, NREL), 256, 0, stream>>>(es, ed, dinv_out, dinv_in);
        k_finalize_deg<<<(2 * NRN + 255) / 256, 256, 0, stream>>>(wsf);

        for (int r = 0; r < NREL; ++r) {
            k_project1<<<1024, 256, 0, stream>>>(
                x, W0 + (size_t)r * F_IN * F_HID, dinv_out + (size_t)r * N_NODES, hproj);
            k_scatter1<<<E_PER / 4, 256, 0, stream>>>(
                hproj, es + (size_t)r * E_PER, ed + (size_t)r * E_PER,
                dinv_in + (size_t)r * N_NODES, h1acc);
        }
        for (int r = 0; r < NREL; ++r) {
            k_project2<<<512, 256, 0, stream>>>(
                h1acc, b0, Wmu + (size_t)r * F_HID * F_OUT,
                Wls + (size_t)r * F_HID * F_OUT, dinv_out + (size_t)r * N_NODES, hproj);
            k_scatter2<<<E_PER / 8, 256, 0, stream>>>(
                hproj, es + (size_t)r * E_PER, ed + (size_t)r * E_PER,
                dinv_in + (size_t)r * N_NODES, l2acc);
        }
        k_finalize<<<N_NODES * F_OUT / 256, 256, 0, stream>>>(
            l2acc, bmu, bls, out + 2 * EP);
        k_scores<<<(2 * EP + 255) / 256, 256, 0, stream>>>(
            ps, pd, ns, nd, out + 2 * EP, out);
    }
}